// Round 17
// baseline (1602.992 us; speedup 1.0000x reference)
//
#include <hip/hip_runtime.h>
#include <math.h>

#define C_LEN 1024
#define NROW 4096
#define NCHUNK 32
#define CHUNK 32

typedef __attribute__((ext_vector_type(8))) short short8;
typedef __attribute__((ext_vector_type(4))) float f32x4;

__device__ __forceinline__ float siluf(float x) { return x / (1.f + __expf(-x)); }

__device__ __forceinline__ unsigned short f2bf(float f) {
    unsigned u = __builtin_bit_cast(unsigned, f);
    unsigned r = (u + 0x7FFFu + ((u >> 16) & 1u)) >> 16;
    return (unsigned short)r;
}
__device__ __forceinline__ float bf2f(unsigned short v) {
    unsigned u = ((unsigned)v) << 16;
    return __builtin_bit_cast(float, u);
}

// ---------------- prep: weights->bf16 + top rmsnorm + scan-flag clear ----------------
struct WTab {
    const float* s[11];
    unsigned short* d[11];
    int n[11];
};
__global__ __launch_bounds__(256) void k_prep(WTab t, const float* __restrict__ x,
                                              const float* __restrict__ nw,
                                              unsigned short* __restrict__ xn_bf,
                                              int* __restrict__ flags) {
    int seg = blockIdx.y;
    if (seg < 11) {
        int n = t.n[seg];
        int i = (blockIdx.x * 256 + threadIdx.x) * 4;
        if (i < n) {
            float4 v = *(const float4*)(t.s[seg] + i);
            unsigned short* o = t.d[seg] + i;
            o[0] = f2bf(v.x); o[1] = f2bf(v.y); o[2] = f2bf(v.z); o[3] = f2bf(v.w);
        }
    } else {
        if (blockIdx.x == 0) {
            for (int i = threadIdx.x; i < 1056; i += 256) flags[i] = 0;
        }
        int wave = threadIdx.x >> 6, lane = threadIdx.x & 63;
        #pragma unroll
        for (int it = 0; it < 4; ++it) {
            int row = blockIdx.x * 16 + it * 4 + wave;
            float2 v = ((const float2*)(x + (size_t)row * 128))[lane];
            float ss = v.x * v.x + v.y * v.y;
            #pragma unroll
            for (int off = 32; off; off >>= 1) ss += __shfl_xor(ss, off, 64);
            float rs = rsqrtf(ss * (1.f / 128.f) + 1e-5f);
            float2 wv = ((const float2*)nw)[lane];
            ushort2 o;
            o.x = f2bf(v.x * rs * wv.x);
            o.y = f2bf(v.y * rs * wv.y);
            ((ushort2*)(xn_bf + (size_t)row * 128))[lane] = o;
        }
    }
}

// ---------------- 64x64 bf16 GEMM (step 2): bf16 out + bias ----------------
__global__ __launch_bounds__(256) void k_gemm_bf(const unsigned short* __restrict__ A,
                                                 const unsigned short* __restrict__ W,
                                                 const float* __restrict__ bias,
                                                 unsigned short* __restrict__ Cbf,
                                                 int N, int K) {
    __shared__ __align__(16) unsigned short As[64 * 72];
    __shared__ __align__(16) unsigned short Bs[64 * 72];
    int tid = threadIdx.x;
    int m0 = blockIdx.y * 64, n0 = blockIdx.x * 64;
    int w = tid >> 6, lane = tid & 63;
    int q = lane >> 4, ln = lane & 15;
    int srow = tid >> 2;
    int sseg = (tid & 3) * 16;

    const unsigned short* pa = A + (size_t)(m0 + srow) * K + sseg;
    const unsigned short* pw = W + (size_t)(n0 + srow) * K + sseg;

    f32x4 acc[4];
    #pragma unroll
    for (int j = 0; j < 4; ++j) acc[j] = (f32x4)(0.f);

    for (int k0 = 0; k0 < K; k0 += 64) {
        *(short8*)&As[srow * 72 + sseg]     = *(const short8*)pa;
        *(short8*)&As[srow * 72 + sseg + 8] = *(const short8*)(pa + 8);
        *(short8*)&Bs[srow * 72 + sseg]     = *(const short8*)pw;
        *(short8*)&Bs[srow * 72 + sseg + 8] = *(const short8*)(pw + 8);
        pa += 64; pw += 64;
        __syncthreads();
        short8 af0 = *(const short8*)&As[(w * 16 + ln) * 72 + q * 8];
        short8 af1 = *(const short8*)&As[(w * 16 + ln) * 72 + 32 + q * 8];
        #pragma unroll
        for (int j = 0; j < 4; ++j) {
            short8 bf0 = *(const short8*)&Bs[(j * 16 + ln) * 72 + q * 8];
            short8 bf1 = *(const short8*)&Bs[(j * 16 + ln) * 72 + 32 + q * 8];
            acc[j] = __builtin_amdgcn_mfma_f32_16x16x32_bf16(af0, bf0, acc[j], 0, 0, 0);
            acc[j] = __builtin_amdgcn_mfma_f32_16x16x32_bf16(af1, bf1, acc[j], 0, 0, 0);
        }
        __syncthreads();
    }
    #pragma unroll
    for (int j = 0; j < 4; ++j) {
        int nn = n0 + j * 16 + ln;
        float bsv = bias[nn];
        #pragma unroll
        for (int r = 0; r < 4; ++r) {
            int m = m0 + w * 16 + q * 4 + r;
            Cbf[(size_t)m * N + nn] = f2bf(acc[j][r] + bsv);
        }
    }
}

// ---------------- 3-way GEMM: z=0 uf (W_fp), z=1 ub (W_bp, flip), z=2 wbuf (W_wp, silu) ----
__global__ __launch_bounds__(256) void k_gemm3(
        const unsigned short* __restrict__ xn, const unsigned short* __restrict__ ssm,
        const unsigned short* __restrict__ Wfp, const unsigned short* __restrict__ Wbp,
        const unsigned short* __restrict__ Wwp,
        const float* __restrict__ bfp, const float* __restrict__ bbp,
        const float* __restrict__ bwp,
        unsigned short* __restrict__ uf, unsigned short* __restrict__ ub,
        unsigned short* __restrict__ wbuf) {
    __shared__ __align__(16) unsigned short As[64 * 72];
    __shared__ __align__(16) unsigned short Bs[64 * 72];
    int z = blockIdx.z;
    const unsigned short* A = (z == 2) ? xn : ssm;
    const unsigned short* W = (z == 0) ? Wfp : (z == 1) ? Wbp : Wwp;
    const float* bias = (z == 0) ? bfp : (z == 1) ? bbp : bwp;
    unsigned short* C = (z == 0) ? uf : (z == 1) ? ub : wbuf;
    int K = (z == 2) ? 128 : 256;
    int tid = threadIdx.x;
    int m0 = blockIdx.y * 64, n0 = blockIdx.x * 64;
    int w = tid >> 6, lane = tid & 63;
    int q = lane >> 4, ln = lane & 15;
    int srow = tid >> 2;
    int sseg = (tid & 3) * 16;

    int mLog = m0 + srow;
    int mPhys = (z == 1) ? (mLog ^ (C_LEN - 1)) : mLog;
    const unsigned short* pa = A + (size_t)mPhys * K + sseg;
    const unsigned short* pw = W + (size_t)(n0 + srow) * K + sseg;

    f32x4 acc[4];
    #pragma unroll
    for (int j = 0; j < 4; ++j) acc[j] = (f32x4)(0.f);

    for (int k0 = 0; k0 < K; k0 += 64) {
        *(short8*)&As[srow * 72 + sseg]     = *(const short8*)pa;
        *(short8*)&As[srow * 72 + sseg + 8] = *(const short8*)(pa + 8);
        *(short8*)&Bs[srow * 72 + sseg]     = *(const short8*)pw;
        *(short8*)&Bs[srow * 72 + sseg + 8] = *(const short8*)(pw + 8);
        pa += 64; pw += 64;
        __syncthreads();
        short8 af0 = *(const short8*)&As[(w * 16 + ln) * 72 + q * 8];
        short8 af1 = *(const short8*)&As[(w * 16 + ln) * 72 + 32 + q * 8];
        #pragma unroll
        for (int j = 0; j < 4; ++j) {
            short8 bf0 = *(const short8*)&Bs[(j * 16 + ln) * 72 + q * 8];
            short8 bf1 = *(const short8*)&Bs[(j * 16 + ln) * 72 + 32 + q * 8];
            acc[j] = __builtin_amdgcn_mfma_f32_16x16x32_bf16(af0, bf0, acc[j], 0, 0, 0);
            acc[j] = __builtin_amdgcn_mfma_f32_16x16x32_bf16(af1, bf1, acc[j], 0, 0, 0);
        }
        __syncthreads();
    }
    #pragma unroll
    for (int j = 0; j < 4; ++j) {
        int nn = n0 + j * 16 + ln;
        float bsv = bias[nn];
        #pragma unroll
        for (int r = 0; r < 4; ++r) {
            int m = m0 + w * 16 + q * 4 + r;
            float v = acc[j][r] + bsv;
            if (z == 2) v = siluf(v);
            C[(size_t)m * 256 + nn] = f2bf(v);
        }
    }
}

// ---------------- 128x64 bf16 GEMM, batched pair (big stages: xz, mo) ----------------
__global__ __launch_bounds__(256) void k_gemm128(
        const unsigned short* __restrict__ A0, const unsigned short* __restrict__ A1,
        const unsigned short* __restrict__ W0, const unsigned short* __restrict__ W1,
        unsigned short* __restrict__ Cb0, unsigned short* __restrict__ Cb1,
        int N, int K) {
    __shared__ __align__(16) unsigned short As[128 * 72];
    __shared__ __align__(16) unsigned short Bs[64 * 72];
    int p = blockIdx.z;
    const unsigned short* A = p ? A1 : A0;
    const unsigned short* W = p ? W1 : W0;
    unsigned short* Cbf = p ? Cb1 : Cb0;
    int tid = threadIdx.x;
    int m0 = blockIdx.y * 128, n0 = blockIdx.x * 64;
    int w = tid >> 6, lane = tid & 63;
    int q = lane >> 4, ln = lane & 15;

    int arow0 = tid >> 1;
    int aseg0 = (tid & 1) * 32;
    int brow = tid >> 2, bseg = (tid & 3) * 16;
    const unsigned short* pa = A + (size_t)(m0 + arow0) * K + aseg0;
    const unsigned short* pw = W + (size_t)(n0 + brow) * K + bseg;

    f32x4 acc[2][4];
    #pragma unroll
    for (int i = 0; i < 2; ++i)
        #pragma unroll
        for (int j = 0; j < 4; ++j) acc[i][j] = (f32x4)(0.f);

    for (int k0 = 0; k0 < K; k0 += 64) {
        #pragma unroll
        for (int h = 0; h < 4; ++h)
            *(short8*)&As[arow0 * 72 + aseg0 + h * 8] = *(const short8*)(pa + h * 8);
        *(short8*)&Bs[brow * 72 + bseg]     = *(const short8*)pw;
        *(short8*)&Bs[brow * 72 + bseg + 8] = *(const short8*)(pw + 8);
        pa += 64; pw += 64;
        __syncthreads();
        short8 a0[2], a1[2];
        #pragma unroll
        for (int i = 0; i < 2; ++i) {
            int row = w * 32 + i * 16 + ln;
            a0[i] = *(const short8*)&As[row * 72 + q * 8];
            a1[i] = *(const short8*)&As[row * 72 + 32 + q * 8];
        }
        #pragma unroll
        for (int j = 0; j < 4; ++j) {
            short8 bf0 = *(const short8*)&Bs[(j * 16 + ln) * 72 + q * 8];
            short8 bf1 = *(const short8*)&Bs[(j * 16 + ln) * 72 + 32 + q * 8];
            #pragma unroll
            for (int i = 0; i < 2; ++i) {
                acc[i][j] = __builtin_amdgcn_mfma_f32_16x16x32_bf16(a0[i], bf0, acc[i][j], 0, 0, 0);
                acc[i][j] = __builtin_amdgcn_mfma_f32_16x16x32_bf16(a1[i], bf1, acc[i][j], 0, 0, 0);
            }
        }
        __syncthreads();
    }
    #pragma unroll
    for (int i = 0; i < 2; ++i)
        #pragma unroll
        for (int j = 0; j < 4; ++j) {
            int nn = n0 + j * 16 + ln;
            #pragma unroll
            for (int r = 0; r < 4; ++r) {
                int m = m0 + w * 32 + i * 16 + q * 4 + r;
                Cbf[(size_t)m * N + nn] = f2bf(acc[i][j][r]);
            }
        }
}

// ---------------- 64x64 pair GEMM, fp32 out (dbl stage) ----------------
__global__ __launch_bounds__(256) void k_gemm2f(
        const unsigned short* __restrict__ A0, const unsigned short* __restrict__ A1,
        const unsigned short* __restrict__ W0, const unsigned short* __restrict__ W1,
        float* __restrict__ Cf0, float* __restrict__ Cf1,
        int N, int K) {
    __shared__ __align__(16) unsigned short As[64 * 72];
    __shared__ __align__(16) unsigned short Bs[64 * 72];
    int p = blockIdx.z;
    const unsigned short* A = p ? A1 : A0;
    const unsigned short* W = p ? W1 : W0;
    float* Cf = p ? Cf1 : Cf0;
    int tid = threadIdx.x;
    int m0 = blockIdx.y * 64, n0 = blockIdx.x * 64;
    int w = tid >> 6, lane = tid & 63;
    int q = lane >> 4, ln = lane & 15;
    int srow = tid >> 2;
    int sseg = (tid & 3) * 16;

    const unsigned short* pa = A + (size_t)(m0 + srow) * K + sseg;
    int nIdx = n0 + srow;
    const unsigned short* pw = W + (size_t)nIdx * K + sseg;
    bool nOK = (nIdx < N);

    f32x4 acc[4];
    #pragma unroll
    for (int j = 0; j < 4; ++j) acc[j] = (f32x4)(0.f);

    for (int k0 = 0; k0 < K; k0 += 64) {
        *(short8*)&As[srow * 72 + sseg]     = *(const short8*)pa;
        *(short8*)&As[srow * 72 + sseg + 8] = *(const short8*)(pa + 8);
        short8 b0 = (short8)(0), b1 = (short8)(0);
        if (nOK) { b0 = *(const short8*)pw; b1 = *(const short8*)(pw + 8); }
        *(short8*)&Bs[srow * 72 + sseg] = b0;
        *(short8*)&Bs[srow * 72 + sseg + 8] = b1;
        pa += 64; pw += 64;
        __syncthreads();
        short8 af0 = *(const short8*)&As[(w * 16 + ln) * 72 + q * 8];
        short8 af1 = *(const short8*)&As[(w * 16 + ln) * 72 + 32 + q * 8];
        #pragma unroll
        for (int j = 0; j < 4; ++j) {
            short8 bf0 = *(const short8*)&Bs[(j * 16 + ln) * 72 + q * 8];
            short8 bf1 = *(const short8*)&Bs[(j * 16 + ln) * 72 + 32 + q * 8];
            acc[j] = __builtin_amdgcn_mfma_f32_16x16x32_bf16(af0, bf0, acc[j], 0, 0, 0);
            acc[j] = __builtin_amdgcn_mfma_f32_16x16x32_bf16(af1, bf1, acc[j], 0, 0, 0);
        }
        __syncthreads();
    }
    #pragma unroll
    for (int j = 0; j < 4; ++j) {
        int nn = n0 + j * 16 + ln;
        if (nn < N) {
            #pragma unroll
            for (int r = 0; r < 4; ++r) {
                int m = m0 + w * 16 + q * 4 + r;
                Cf[(size_t)m * N + nn] = acc[j][r];
            }
        }
    }
}

// ---------------- final GEMM with comb fused into A-staging ----------------
__global__ __launch_bounds__(256) void k_gemm_comb(const unsigned short* __restrict__ wbuf,
                                                   const unsigned short* __restrict__ mof,
                                                   const unsigned short* __restrict__ mob,
                                                   const unsigned short* __restrict__ W,
                                                   const float* __restrict__ bias,
                                                   const float* __restrict__ resid,
                                                   float* __restrict__ Cf,
                                                   int N, int K) {
    __shared__ __align__(16) unsigned short As[64 * 72];
    __shared__ __align__(16) unsigned short Bs[64 * 72];
    int tid = threadIdx.x;
    int m0 = blockIdx.y * 64, n0 = blockIdx.x * 64;
    int w = tid >> 6, lane = tid & 63;
    int q = lane >> 4, ln = lane & 15;
    int srow = tid >> 2;
    int sseg = (tid & 3) * 16;

    int mLog = m0 + srow;
    int mFlip = mLog ^ (C_LEN - 1);
    int nIdx = n0 + srow;
    const unsigned short* pw = W + (size_t)nIdx * K + sseg;
    bool nOK = (nIdx < N);

    f32x4 acc[4];
    #pragma unroll
    for (int j = 0; j < 4; ++j) acc[j] = (f32x4)(0.f);

    for (int k0 = 0; k0 < K; k0 += 64) {
        size_t off  = (size_t)mLog * 256 + k0 + sseg;
        size_t offb = (size_t)mFlip * 256 + k0 + sseg;
        #pragma unroll
        for (int h = 0; h < 2; ++h) {
            short8 aw = *(const short8*)(wbuf + off + h * 8);
            short8 af = *(const short8*)(mof + off + h * 8);
            short8 ab = *(const short8*)(mob + offb + h * 8);
            short8 av;
            #pragma unroll
            for (int j = 0; j < 8; ++j)
                av[j] = (short)f2bf(bf2f((unsigned short)aw[j]) *
                                    (bf2f((unsigned short)af[j]) + bf2f((unsigned short)ab[j])));
            *(short8*)&As[srow * 72 + sseg + h * 8] = av;
        }
        short8 b0 = (short8)(0), b1 = (short8)(0);
        if (nOK) { b0 = *(const short8*)pw; b1 = *(const short8*)(pw + 8); }
        *(short8*)&Bs[srow * 72 + sseg] = b0;
        *(short8*)&Bs[srow * 72 + sseg + 8] = b1;
        pw += 64;
        __syncthreads();
        short8 af0 = *(const short8*)&As[(w * 16 + ln) * 72 + q * 8];
        short8 af1 = *(const short8*)&As[(w * 16 + ln) * 72 + 32 + q * 8];
        #pragma unroll
        for (int j = 0; j < 4; ++j) {
            short8 bf0 = *(const short8*)&Bs[(j * 16 + ln) * 72 + q * 8];
            short8 bf1 = *(const short8*)&Bs[(j * 16 + ln) * 72 + 32 + q * 8];
            acc[j] = __builtin_amdgcn_mfma_f32_16x16x32_bf16(af0, bf0, acc[j], 0, 0, 0);
            acc[j] = __builtin_amdgcn_mfma_f32_16x16x32_bf16(af1, bf1, acc[j], 0, 0, 0);
        }
        __syncthreads();
    }
    #pragma unroll
    for (int j = 0; j < 4; ++j) {
        int nn = n0 + j * 16 + ln;
        if (nn < N) {
            float bsv = bias[nn];
            #pragma unroll
            for (int r = 0; r < 4; ++r) {
                int m = m0 + w * 16 + q * 4 + r;
                Cf[(size_t)m * N + nn] = acc[j][r] + bsv + resid[(size_t)m * N + nn];
            }
        }
    }
}

// ---------------- causal depthwise conv (K=4) + silu, both blocks ----------------
__global__ __launch_bounds__(256) void k_conv(const unsigned short* __restrict__ xz0,
                                              const unsigned short* __restrict__ xz1,
                                              const float* __restrict__ cw0,
                                              const float* __restrict__ cw1,
                                              const float* __restrict__ cb0,
                                              const float* __restrict__ cb1,
                                              unsigned short* __restrict__ xc0,
                                              unsigned short* __restrict__ xc1) {
    int pz = blockIdx.z;
    const unsigned short* xz = pz ? xz1 : xz0;
    const float* cw = pz ? cw1 : cw0;
    const float* cb = pz ? cb1 : cb0;
    unsigned short* xconv_bf = pz ? xc1 : xc0;
    int d = blockIdx.x * 256 + threadIdx.x;
    int by = blockIdx.y;
    int b = by >> 6, c0 = (by & 63) * 16;
    float4 cwv = *(const float4*)(cw + d * 4);
    float bias = cb[d];
    const unsigned short* base = xz + (size_t)(b * C_LEN) * 1024 + d;
    float w0 = 0.f, w1 = 0.f, w2 = 0.f;
    if (c0) {
        w0 = bf2f(base[(size_t)(c0 - 3) * 1024]);
        w1 = bf2f(base[(size_t)(c0 - 2) * 1024]);
        w2 = bf2f(base[(size_t)(c0 - 1) * 1024]);
    }
    unsigned short* out = xconv_bf + (size_t)(b * C_LEN + c0) * 512 + d;
    #pragma unroll
    for (int i = 0; i < 16; ++i) {
        float cur = bf2f(base[(size_t)(c0 + i) * 1024]);
        float acc = bias;
        acc = fmaf(cwv.x, w0, acc);
        acc = fmaf(cwv.y, w1, acc);
        acc = fmaf(cwv.z, w2, acc);
        acc = fmaf(cwv.w, cur, acc);
        out[(size_t)i * 512] = f2bf(siluf(acc));
        w0 = w1; w1 = w2; w2 = cur;
    }
}

// ---------------- dt projection -> bf16, 8 rows per thread, both blocks ----------------
__global__ __launch_bounds__(256) void k_dtproj(const float* __restrict__ dbl0,
                                                const float* __restrict__ dbl1,
                                                const float* __restrict__ dtw0,
                                                const float* __restrict__ dtw1,
                                                const float* __restrict__ dtb0,
                                                const float* __restrict__ dtb1,
                                                unsigned short* __restrict__ dt0,
                                                unsigned short* __restrict__ dt1) {
    int pz = blockIdx.z;
    const float* dbl = pz ? dbl1 : dbl0;
    const float* dtw = pz ? dtw1 : dtw0;
    const float* dtb = pz ? dtb1 : dtb0;
    unsigned short* dt = pz ? dt1 : dt0;
    int d = blockIdx.x * 256 + threadIdx.x;
    int r0 = blockIdx.y * 8;
    float4 w0 = *(const float4*)(dtw + d * 16);
    float4 w1 = *(const float4*)(dtw + d * 16 + 4);
    float4 w2 = *(const float4*)(dtw + d * 16 + 8);
    float4 w3 = *(const float4*)(dtw + d * 16 + 12);
    float bias = dtb[d];
    #pragma unroll
    for (int rr = 0; rr < 8; ++rr) {
        int r = r0 + rr;
        const float* row = dbl + (size_t)r * 48;
        float s = bias;
        s = fmaf(row[0], w0.x, s);  s = fmaf(row[1], w0.y, s);
        s = fmaf(row[2], w0.z, s);  s = fmaf(row[3], w0.w, s);
        s = fmaf(row[4], w1.x, s);  s = fmaf(row[5], w1.y, s);
        s = fmaf(row[6], w1.z, s);  s = fmaf(row[7], w1.w, s);
        s = fmaf(row[8], w2.x, s);  s = fmaf(row[9], w2.y, s);
        s = fmaf(row[10], w2.z, s); s = fmaf(row[11], w2.w, s);
        s = fmaf(row[12], w3.x, s); s = fmaf(row[13], w3.y, s);
        s = fmaf(row[14], w3.z, s); s = fmaf(row[15], w3.w, s);
        float sp = fmaxf(s, 0.f) + log1pf(__expf(-fabsf(s)));
        dt[(size_t)r * 512 + d] = f2bf(sp);
    }
}

// ---------------- fused selective scan: local scan + combine + replay in ONE launch ------
// grid (NCHUNK, 4 dgroups, 8 bp); 1024 blocks x 4 waves = 4096 waves << 8192-wave capacity,
// so the whole grid is co-resident (required for the flag protocol; AMD dispatches
// workgroups in ascending ID order). Chunk-0 blocks perform the scan2 combine for their
// (d,n)-slice and publish carries in-place into Pfin.
__global__ __launch_bounds__(256) void k_scanfused(
        const unsigned short* __restrict__ dt0, const unsigned short* __restrict__ dt1,
        const unsigned short* __restrict__ xc0, const unsigned short* __restrict__ xc1,
        const float* __restrict__ dblA, const float* __restrict__ dblB,
        const unsigned short* __restrict__ xz0, const unsigned short* __restrict__ xz1,
        const float* __restrict__ alog0, const float* __restrict__ alog1,
        const float* __restrict__ Dp0, const float* __restrict__ Dp1,
        float* __restrict__ hfin0, float* __restrict__ hfin1,
        float* __restrict__ Pfin0, float* __restrict__ Pfin1,
        unsigned short* __restrict__ g0, unsigned short* __restrict__ g1,
        int* __restrict__ flags) {
    __shared__ int sflag;
    int z = blockIdx.z;
    int b = z & 3, p = z >> 2;
    const unsigned short* dt = p ? dt1 : dt0;
    const unsigned short* xconv_bf = p ? xc1 : xc0;
    const float* dbl = p ? dblB : dblA;
    const unsigned short* xz = p ? xz1 : xz0;
    const float* A_log = p ? alog1 : alog0;
    const float* Dp = p ? Dp1 : Dp0;
    float* hfin = p ? hfin1 : hfin0;
    float* Pfin = p ? Pfin1 : Pfin0;
    unsigned short* gated_bf = p ? g1 : g0;
    int tid = threadIdx.x;
    int nh = tid & 1, dl = tid >> 1;
    int k = blockIdx.x, dg = blockIdx.y;
    int d = dg * 128 + dl;
    float4 al0 = *(const float4*)&A_log[d * 16 + nh * 8];
    float4 al1 = *(const float4*)&A_log[d * 16 + nh * 8 + 4];
    float Ac[8] = {-__expf(al0.x), -__expf(al0.y), -__expf(al0.z), -__expf(al0.w),
                   -__expf(al1.x), -__expf(al1.y), -__expf(al1.z), -__expf(al1.w)};
    float Dd = Dp[d];
    int slice = z * 4 + dg;          // 0..31
    int pubBase = slice * 32;        // publish flags [slice][k]
    int readyIdx = 1024 + slice;     // carry-ready flag per slice

    // ---- pass 1: local chunk scan ----
    size_t r0 = (size_t)(b * C_LEN + k * CHUNK);
    {
        const unsigned short* pdt = dt + r0 * 512 + d;
        const unsigned short* pxv = xconv_bf + r0 * 512 + d;
        const float* pB = dbl + r0 * 48 + 16 + nh * 8;
        float h[8] = {0.f, 0.f, 0.f, 0.f, 0.f, 0.f, 0.f, 0.f};
        float sdt = 0.f;
        #pragma unroll 8
        for (int c = 0; c < CHUNK; ++c) {
            float dtv = bf2f(*pdt);
            float xv  = bf2f(*pxv);
            float4 B0 = *(const float4*)pB;
            float4 B1 = *(const float4*)(pB + 4);
            float dx = dtv * xv;
            float Bv[8] = {B0.x, B0.y, B0.z, B0.w, B1.x, B1.y, B1.z, B1.w};
            #pragma unroll
            for (int j = 0; j < 8; ++j)
                h[j] = fmaf(__expf(dtv * Ac[j]), h[j], dx * Bv[j]);
            sdt += dtv;
            pdt += 512; pxv += 512; pB += 48;
        }
        size_t idx = ((size_t)(b * NCHUNK + k) * 512 + d) * 16 + nh * 8;
        *(float4*)&hfin[idx]     = make_float4(h[0], h[1], h[2], h[3]);
        *(float4*)&hfin[idx + 4] = make_float4(h[4], h[5], h[6], h[7]);
        *(float4*)&Pfin[idx]     = make_float4(__expf(Ac[0] * sdt), __expf(Ac[1] * sdt),
                                               __expf(Ac[2] * sdt), __expf(Ac[3] * sdt));
        *(float4*)&Pfin[idx + 4] = make_float4(__expf(Ac[4] * sdt), __expf(Ac[5] * sdt),
                                               __expf(Ac[6] * sdt), __expf(Ac[7] * sdt));
    }
    __threadfence();
    __syncthreads();
    if (tid == 0)
        __hip_atomic_store(&flags[pubBase + k], 1, __ATOMIC_RELEASE, __HIP_MEMORY_SCOPE_AGENT);

    // ---- combine (chunk-0 blocks) or wait for carry ----
    float h[8];
    if (k == 0) {
        if (tid == 0) {
            for (int j = 1; j < NCHUNK; ++j) {
                long spin = 0;
                while (__hip_atomic_load(&flags[pubBase + j], __ATOMIC_ACQUIRE,
                                         __HIP_MEMORY_SCOPE_AGENT) == 0) {
                    __builtin_amdgcn_s_sleep(8);
                    if (++spin > (1L << 27)) break;   // bounded: fail as wrong-answer, not hang
                }
            }
        }
        __syncthreads();
        // sequential combine over chunks for my (d, nh*8) slice (scan2 math, in-place)
        float carry[8] = {0.f, 0.f, 0.f, 0.f, 0.f, 0.f, 0.f, 0.f};
        size_t cbase = ((size_t)(b * NCHUNK) * 512 + d) * 16 + nh * 8;
        for (int k2 = 0; k2 < NCHUNK; ++k2) {
            size_t idx2 = cbase + (size_t)k2 * 8192;
            float4 P0 = *(const float4*)&Pfin[idx2];
            float4 P1 = *(const float4*)&Pfin[idx2 + 4];
            float4 H0 = *(const float4*)&hfin[idx2];
            float4 H1 = *(const float4*)&hfin[idx2 + 4];
            *(float4*)&Pfin[idx2]     = make_float4(carry[0], carry[1], carry[2], carry[3]);
            *(float4*)&Pfin[idx2 + 4] = make_float4(carry[4], carry[5], carry[6], carry[7]);
            float Pv[8] = {P0.x, P0.y, P0.z, P0.w, P1.x, P1.y, P1.z, P1.w};
            float Hv[8] = {H0.x, H0.y, H0.z, H0.w, H1.x, H1.y, H1.z, H1.w};
            #pragma unroll
            for (int s = 0; s < 8; ++s) carry[s] = fmaf(Pv[s], carry[s], Hv[s]);
        }
        __threadfence();
        __syncthreads();
        if (tid == 0)
            __hip_atomic_store(&flags[readyIdx], 1, __ATOMIC_RELEASE, __HIP_MEMORY_SCOPE_AGENT);
        #pragma unroll
        for (int s = 0; s < 8; ++s) h[s] = 0.f;     // chunk 0 carry-in = 0
    } else {
        if (tid == 0) {
            long spin = 0;
            int v;
            do {
                v = __hip_atomic_load(&flags[readyIdx], __ATOMIC_ACQUIRE,
                                      __HIP_MEMORY_SCOPE_AGENT);
                if (v == 0) __builtin_amdgcn_s_sleep(8);
            } while (v == 0 && ++spin < (1L << 27));
            sflag = v;
        }
        __syncthreads();
        size_t idx = ((size_t)(b * NCHUNK + k) * 512 + d) * 16 + nh * 8;
        float4 h0v = *(const float4*)&Pfin[idx];
        float4 h1v = *(const float4*)&Pfin[idx + 4];
        h[0] = h0v.x; h[1] = h0v.y; h[2] = h0v.z; h[3] = h0v.w;
        h[4] = h1v.x; h[5] = h1v.y; h[6] = h1v.z; h[7] = h1v.w;
    }

    // ---- pass 2: replay with carry-in ----
    {
        const unsigned short* pdt = dt + r0 * 512 + d;
        const unsigned short* pxv = xconv_bf + r0 * 512 + d;
        const float* pB = dbl + r0 * 48 + 16 + nh * 8;
        const float* pC = dbl + r0 * 48 + 32 + nh * 8;
        const unsigned short* pz = xz + r0 * 1024 + 512 + d;
        unsigned short* pg = gated_bf + r0 * 512 + d;
        #pragma unroll 4
        for (int c = 0; c < CHUNK; ++c) {
            float dtv = bf2f(*pdt);
            float xv  = bf2f(*pxv);
            float4 B0 = *(const float4*)pB;
            float4 B1 = *(const float4*)(pB + 4);
            float4 C0 = *(const float4*)pC;
            float4 C1 = *(const float4*)(pC + 4);
            float dx = dtv * xv;
            float Bv[8] = {B0.x, B0.y, B0.z, B0.w, B1.x, B1.y, B1.z, B1.w};
            float Cv[8] = {C0.x, C0.y, C0.z, C0.w, C1.x, C1.y, C1.z, C1.w};
            float contrib = 0.f;
            #pragma unroll
            for (int j = 0; j < 8; ++j) {
                h[j] = fmaf(__expf(dtv * Ac[j]), h[j], dx * Bv[j]);
                contrib = fmaf(h[j], Cv[j], contrib);
            }
            contrib += __shfl_xor(contrib, 1, 64);
            if (nh == 0) {
                float y = contrib + xv * Dd;
                float zv = bf2f(*pz);
                *pg = f2bf(y * siluf(zv));
            }
            pdt += 512; pxv += 512; pB += 48; pC += 48; pz += 1024; pg += 512;
        }
    }
}

// ---------------- postnorm both blocks: rmsnorm(mo)*w + u -> bf16 ----------------
__global__ __launch_bounds__(256) void k_postnorm(const unsigned short* __restrict__ mo0,
                                                  const unsigned short* __restrict__ mo1,
                                                  const float* __restrict__ w0,
                                                  const float* __restrict__ w1,
                                                  const unsigned short* __restrict__ u0,
                                                  const unsigned short* __restrict__ u1,
                                                  unsigned short* __restrict__ o0,
                                                  unsigned short* __restrict__ o1) {
    __shared__ float red[4];
    int p = blockIdx.y;
    const unsigned short* mo = p ? mo1 : mo0;
    const float* w = p ? w1 : w0;
    const unsigned short* u = p ? u1 : u0;
    unsigned short* out = p ? o1 : o0;
    int r = blockIdx.x, tid = threadIdx.x;
    float v = bf2f(mo[(size_t)r * 256 + tid]);
    float ss = v * v;
    #pragma unroll
    for (int off = 32; off; off >>= 1) ss += __shfl_xor(ss, off, 64);
    if ((tid & 63) == 0) red[tid >> 6] = ss;
    __syncthreads();
    float tot = red[0] + red[1] + red[2] + red[3];
    float rs = rsqrtf(tot * (1.f / 256.f) + 1e-5f);
    out[(size_t)r * 256 + tid] = f2bf(v * rs * w[tid] + bf2f(u[(size_t)r * 256 + tid]));
}

extern "C" void kernel_launch(void* const* d_in, const int* in_sizes, int n_in,
                              void* d_out, int out_size, void* d_ws, size_t ws_size,
                              hipStream_t stream) {
    const float* x          = (const float*)d_in[0];
    const float* W_in       = (const float*)d_in[1];
    const float* b_in       = (const float*)d_in[2];
    const float* W_wp       = (const float*)d_in[3];
    const float* b_wp       = (const float*)d_in[4];
    const float* W_fp       = (const float*)d_in[5];
    const float* b_fp       = (const float*)d_in[6];
    const float* W_bp       = (const float*)d_in[7];
    const float* b_bp       = (const float*)d_in[8];
    const float* W_out      = (const float*)d_in[9];
    const float* b_out      = (const float*)d_in[10];
    const float* norm_w_top = (const float*)d_in[11];
    const float* mamba_p[2][10];
    for (int p = 0; p < 2; ++p)
        for (int i = 0; i < 10; ++i)
            mamba_p[p][i] = (const float*)d_in[12 + p * 10 + i];

    // ---- workspace layout ----
    float* ws = (float*)d_ws;
    float* dblP[2]  = {ws + 0,       ws + 196608};
    float* hfinP[2] = {ws + 4587520, ws + 5636096};
    float* PfinP[2] = {ws + 6684672, ws + 7733248};
    unsigned short* dtsP[2] = {(unsigned short*)(ws + 393216),
                               (unsigned short*)(ws + 2490368)};

    unsigned short* us = (unsigned short*)(ws + 8781824);
    unsigned short* xn_bf   = us + 0;
    unsigned short* ssm_bf  = us + 524288;
    unsigned short* uf_bf   = us + 1572864;
    unsigned short* ub_bf   = us + 2621440;
    unsigned short* wbuf_bf = us + 3670016;
    unsigned short* xzP[2]  = {us + 4718592,  us + 8912896};
    unsigned short* xcP[2]  = {us + 13107200, us + 15204352};
    unsigned short* gP[2]   = {us + 17301504, us + 19398656};
    unsigned short* moP[2]  = {us + 21495808, us + 22544384};
    unsigned short* mof_bf  = us + 23592960;
    unsigned short* mob_bf  = us + 24641536;
    unsigned short* wb      = us + 25690112;
    unsigned short* wb_W_in  = wb + 0;
    unsigned short* wb_W_wp  = wb + 32768;
    unsigned short* wb_W_fp  = wb + 65536;
    unsigned short* wb_W_bp  = wb + 131072;
    unsigned short* wb_W_out = wb + 196608;
    unsigned short* wb_in[2]  = {wb + 229376, wb + 647168};
    unsigned short* wb_xp[2]  = {wb + 491520, wb + 909312};
    unsigned short* wb_outw[2]= {wb + 516096, wb + 933888};
    int* flags = (int*)(us + 26755072);   // 1056 ints (cleared by k_prep each launch)

    // 1. weights->bf16 + top rmsnorm + flag clear
    WTab t;
    t.s[0] = W_in;            t.d[0] = wb_W_in;   t.n[0] = 32768;
    t.s[1] = W_wp;            t.d[1] = wb_W_wp;   t.n[1] = 32768;
    t.s[2] = W_fp;            t.d[2] = wb_W_fp;   t.n[2] = 65536;
    t.s[3] = W_bp;            t.d[3] = wb_W_bp;   t.n[3] = 65536;
    t.s[4] = W_out;           t.d[4] = wb_W_out;  t.n[4] = 32768;
    t.s[5] = mamba_p[0][0];   t.d[5] = wb_in[0];  t.n[5] = 262144;
    t.s[6] = mamba_p[0][3];   t.d[6] = wb_xp[0];  t.n[6] = 24576;
    t.s[7] = mamba_p[0][8];   t.d[7] = wb_outw[0];t.n[7] = 131072;
    t.s[8] = mamba_p[1][0];   t.d[8] = wb_in[1];  t.n[8] = 262144;
    t.s[9] = mamba_p[1][3];   t.d[9] = wb_xp[1];  t.n[9] = 24576;
    t.s[10]= mamba_p[1][8];   t.d[10]= wb_outw[1];t.n[10]= 131072;
    k_prep<<<dim3(256, 12), 256, 0, stream>>>(t, x, norm_w_top, xn_bf, flags);

    // 2. ssm = xn @ W_in^T + b_in
    k_gemm_bf<<<dim3(4, 64), 256, 0, stream>>>(xn_bf, wb_W_in, b_in, ssm_bf, 256, 128);
    // 3. uf / ub / wbuf
    k_gemm3<<<dim3(4, 64, 3), 256, 0, stream>>>(xn_bf, ssm_bf, wb_W_fp, wb_W_bp, wb_W_wp,
                                                b_fp, b_bp, b_wp, uf_bf, ub_bf, wbuf_bf);
    // 4. xz = u @ in_w^T (K=256,N=1024), 128x64 tiles
    k_gemm128<<<dim3(16, 32, 2), 256, 0, stream>>>(uf_bf, ub_bf, wb_in[0], wb_in[1],
                                                   xzP[0], xzP[1], 1024, 256);
    // 5. conv + silu
    k_conv<<<dim3(2, 256, 2), 256, 0, stream>>>(xzP[0], xzP[1],
                                                mamba_p[0][1], mamba_p[1][1],
                                                mamba_p[0][2], mamba_p[1][2],
                                                xcP[0], xcP[1]);
    // 6. dbl = xconv @ xproj_w^T (K=512,N=48) -> fp32
    k_gemm2f<<<dim3(1, 64, 2), 256, 0, stream>>>(xcP[0], xcP[1], wb_xp[0], wb_xp[1],
                                                 dblP[0], dblP[1], 48, 512);
    // 7. dt = softplus(...) -> bf16
    k_dtproj<<<dim3(2, 512, 2), 256, 0, stream>>>(dblP[0], dblP[1],
                                                  mamba_p[0][4], mamba_p[1][4],
                                                  mamba_p[0][5], mamba_p[1][5],
                                                  dtsP[0], dtsP[1]);
    // 8. fused scan (local + combine + replay, one launch)
    k_scanfused<<<dim3(NCHUNK, 4, 8), 256, 0, stream>>>(
        dtsP[0], dtsP[1], xcP[0], xcP[1], dblP[0], dblP[1], xzP[0], xzP[1],
        mamba_p[0][6], mamba_p[1][6], mamba_p[0][7], mamba_p[1][7],
        hfinP[0], hfinP[1], PfinP[0], PfinP[1], gP[0], gP[1], flags);
    // 9. mo_raw = gated @ out_w^T (K=512,N=256), 128x64 tiles
    k_gemm128<<<dim3(4, 32, 2), 256, 0, stream>>>(gP[0], gP[1], wb_outw[0], wb_outw[1],
                                                  moP[0], moP[1], 256, 512);
    // 10. postnorm both
    k_postnorm<<<dim3(NROW, 2), 256, 0, stream>>>(moP[0], moP[1],
                                                  mamba_p[0][9], mamba_p[1][9],
                                                  uf_bf, ub_bf, mof_bf, mob_bf);
    // 11. out = [wbuf*(mof+flip(mob))] @ W_out^T + b_out + x
    k_gemm_comb<<<dim3(2, 64), 256, 0, stream>>>(wbuf_bf, mof_bf, mob_bf, wb_W_out, b_out,
                                                 x, (float*)d_out, 128, 256);
}

// Round 18
// 272.616 us; speedup vs baseline: 5.8800x; 5.8800x over previous
//
#include <hip/hip_runtime.h>
#include <math.h>

#define C_LEN 1024
#define NROW 4096
#define NCHUNK 32
#define CHUNK 32

typedef __attribute__((ext_vector_type(8))) short short8;
typedef __attribute__((ext_vector_type(4))) float f32x4;

__device__ __forceinline__ float siluf(float x) { return x / (1.f + __expf(-x)); }

__device__ __forceinline__ unsigned short f2bf(float f) {
    unsigned u = __builtin_bit_cast(unsigned, f);
    unsigned r = (u + 0x7FFFu + ((u >> 16) & 1u)) >> 16;
    return (unsigned short)r;
}
__device__ __forceinline__ float bf2f(unsigned short v) {
    unsigned u = ((unsigned)v) << 16;
    return __builtin_bit_cast(float, u);
}

// ---------------- prep: weight fp32->bf16 (segs 0..10) + top rmsnorm (seg 11) ----------
struct WTab {
    const float* s[11];
    unsigned short* d[11];
    int n[11];
};
__global__ __launch_bounds__(256) void k_prep(WTab t, const float* __restrict__ x,
                                              const float* __restrict__ nw,
                                              unsigned short* __restrict__ xn_bf) {
    int seg = blockIdx.y;
    if (seg < 11) {
        int n = t.n[seg];
        int i = (blockIdx.x * 256 + threadIdx.x) * 4;
        if (i < n) {
            float4 v = *(const float4*)(t.s[seg] + i);
            unsigned short* o = t.d[seg] + i;
            o[0] = f2bf(v.x); o[1] = f2bf(v.y); o[2] = f2bf(v.z); o[3] = f2bf(v.w);
        }
    } else {
        int wave = threadIdx.x >> 6, lane = threadIdx.x & 63;
        #pragma unroll
        for (int it = 0; it < 4; ++it) {
            int row = blockIdx.x * 16 + it * 4 + wave;
            float2 v = ((const float2*)(x + (size_t)row * 128))[lane];
            float ss = v.x * v.x + v.y * v.y;
            #pragma unroll
            for (int off = 32; off; off >>= 1) ss += __shfl_xor(ss, off, 64);
            float rs = rsqrtf(ss * (1.f / 128.f) + 1e-5f);
            float2 wv = ((const float2*)nw)[lane];
            ushort2 o;
            o.x = f2bf(v.x * rs * wv.x);
            o.y = f2bf(v.y * rs * wv.y);
            ((ushort2*)(xn_bf + (size_t)row * 128))[lane] = o;
        }
    }
}

// ---------------- 64x64 bf16 GEMM (step 2): bf16 out + bias ----------------
__global__ __launch_bounds__(256) void k_gemm_bf(const unsigned short* __restrict__ A,
                                                 const unsigned short* __restrict__ W,
                                                 const float* __restrict__ bias,
                                                 unsigned short* __restrict__ Cbf,
                                                 int N, int K) {
    __shared__ __align__(16) unsigned short As[64 * 72];
    __shared__ __align__(16) unsigned short Bs[64 * 72];
    int tid = threadIdx.x;
    int m0 = blockIdx.y * 64, n0 = blockIdx.x * 64;
    int w = tid >> 6, lane = tid & 63;
    int q = lane >> 4, ln = lane & 15;
    int srow = tid >> 2;
    int sseg = (tid & 3) * 16;

    const unsigned short* pa = A + (size_t)(m0 + srow) * K + sseg;
    const unsigned short* pw = W + (size_t)(n0 + srow) * K + sseg;

    f32x4 acc[4];
    #pragma unroll
    for (int j = 0; j < 4; ++j) acc[j] = (f32x4)(0.f);

    for (int k0 = 0; k0 < K; k0 += 64) {
        *(short8*)&As[srow * 72 + sseg]     = *(const short8*)pa;
        *(short8*)&As[srow * 72 + sseg + 8] = *(const short8*)(pa + 8);
        *(short8*)&Bs[srow * 72 + sseg]     = *(const short8*)pw;
        *(short8*)&Bs[srow * 72 + sseg + 8] = *(const short8*)(pw + 8);
        pa += 64; pw += 64;
        __syncthreads();
        short8 af0 = *(const short8*)&As[(w * 16 + ln) * 72 + q * 8];
        short8 af1 = *(const short8*)&As[(w * 16 + ln) * 72 + 32 + q * 8];
        #pragma unroll
        for (int j = 0; j < 4; ++j) {
            short8 bf0 = *(const short8*)&Bs[(j * 16 + ln) * 72 + q * 8];
            short8 bf1 = *(const short8*)&Bs[(j * 16 + ln) * 72 + 32 + q * 8];
            acc[j] = __builtin_amdgcn_mfma_f32_16x16x32_bf16(af0, bf0, acc[j], 0, 0, 0);
            acc[j] = __builtin_amdgcn_mfma_f32_16x16x32_bf16(af1, bf1, acc[j], 0, 0, 0);
        }
        __syncthreads();
    }
    #pragma unroll
    for (int j = 0; j < 4; ++j) {
        int nn = n0 + j * 16 + ln;
        float bsv = bias[nn];
        #pragma unroll
        for (int r = 0; r < 4; ++r) {
            int m = m0 + w * 16 + q * 4 + r;
            Cbf[(size_t)m * N + nn] = f2bf(acc[j][r] + bsv);
        }
    }
}

// ---------------- 3-way GEMM: z=0 uf (W_fp), z=1 ub (W_bp, flip), z=2 wbuf (W_wp, silu) ----
__global__ __launch_bounds__(256) void k_gemm3(
        const unsigned short* __restrict__ xn, const unsigned short* __restrict__ ssm,
        const unsigned short* __restrict__ Wfp, const unsigned short* __restrict__ Wbp,
        const unsigned short* __restrict__ Wwp,
        const float* __restrict__ bfp, const float* __restrict__ bbp,
        const float* __restrict__ bwp,
        unsigned short* __restrict__ uf, unsigned short* __restrict__ ub,
        unsigned short* __restrict__ wbuf) {
    __shared__ __align__(16) unsigned short As[64 * 72];
    __shared__ __align__(16) unsigned short Bs[64 * 72];
    int z = blockIdx.z;
    const unsigned short* A = (z == 2) ? xn : ssm;
    const unsigned short* W = (z == 0) ? Wfp : (z == 1) ? Wbp : Wwp;
    const float* bias = (z == 0) ? bfp : (z == 1) ? bbp : bwp;
    unsigned short* C = (z == 0) ? uf : (z == 1) ? ub : wbuf;
    int K = (z == 2) ? 128 : 256;
    int tid = threadIdx.x;
    int m0 = blockIdx.y * 64, n0 = blockIdx.x * 64;
    int w = tid >> 6, lane = tid & 63;
    int q = lane >> 4, ln = lane & 15;
    int srow = tid >> 2;
    int sseg = (tid & 3) * 16;

    int mLog = m0 + srow;
    int mPhys = (z == 1) ? (mLog ^ (C_LEN - 1)) : mLog;
    const unsigned short* pa = A + (size_t)mPhys * K + sseg;
    const unsigned short* pw = W + (size_t)(n0 + srow) * K + sseg;

    f32x4 acc[4];
    #pragma unroll
    for (int j = 0; j < 4; ++j) acc[j] = (f32x4)(0.f);

    for (int k0 = 0; k0 < K; k0 += 64) {
        *(short8*)&As[srow * 72 + sseg]     = *(const short8*)pa;
        *(short8*)&As[srow * 72 + sseg + 8] = *(const short8*)(pa + 8);
        *(short8*)&Bs[srow * 72 + sseg]     = *(const short8*)pw;
        *(short8*)&Bs[srow * 72 + sseg + 8] = *(const short8*)(pw + 8);
        pa += 64; pw += 64;
        __syncthreads();
        short8 af0 = *(const short8*)&As[(w * 16 + ln) * 72 + q * 8];
        short8 af1 = *(const short8*)&As[(w * 16 + ln) * 72 + 32 + q * 8];
        #pragma unroll
        for (int j = 0; j < 4; ++j) {
            short8 bf0 = *(const short8*)&Bs[(j * 16 + ln) * 72 + q * 8];
            short8 bf1 = *(const short8*)&Bs[(j * 16 + ln) * 72 + 32 + q * 8];
            acc[j] = __builtin_amdgcn_mfma_f32_16x16x32_bf16(af0, bf0, acc[j], 0, 0, 0);
            acc[j] = __builtin_amdgcn_mfma_f32_16x16x32_bf16(af1, bf1, acc[j], 0, 0, 0);
        }
        __syncthreads();
    }
    #pragma unroll
    for (int j = 0; j < 4; ++j) {
        int nn = n0 + j * 16 + ln;
        float bsv = bias[nn];
        #pragma unroll
        for (int r = 0; r < 4; ++r) {
            int m = m0 + w * 16 + q * 4 + r;
            float v = acc[j][r] + bsv;
            if (z == 2) v = siluf(v);
            C[(size_t)m * 256 + nn] = f2bf(v);
        }
    }
}

// ---------------- 128x64 bf16 GEMM, batched pair (big stages: xz, mo) ----------------
__global__ __launch_bounds__(256) void k_gemm128(
        const unsigned short* __restrict__ A0, const unsigned short* __restrict__ A1,
        const unsigned short* __restrict__ W0, const unsigned short* __restrict__ W1,
        unsigned short* __restrict__ Cb0, unsigned short* __restrict__ Cb1,
        int N, int K) {
    __shared__ __align__(16) unsigned short As[128 * 72];
    __shared__ __align__(16) unsigned short Bs[64 * 72];
    int p = blockIdx.z;
    const unsigned short* A = p ? A1 : A0;
    const unsigned short* W = p ? W1 : W0;
    unsigned short* Cbf = p ? Cb1 : Cb0;
    int tid = threadIdx.x;
    int m0 = blockIdx.y * 128, n0 = blockIdx.x * 64;
    int w = tid >> 6, lane = tid & 63;
    int q = lane >> 4, ln = lane & 15;

    int arow0 = tid >> 1;
    int aseg0 = (tid & 1) * 32;
    int brow = tid >> 2, bseg = (tid & 3) * 16;
    const unsigned short* pa = A + (size_t)(m0 + arow0) * K + aseg0;
    const unsigned short* pw = W + (size_t)(n0 + brow) * K + bseg;

    f32x4 acc[2][4];
    #pragma unroll
    for (int i = 0; i < 2; ++i)
        #pragma unroll
        for (int j = 0; j < 4; ++j) acc[i][j] = (f32x4)(0.f);

    for (int k0 = 0; k0 < K; k0 += 64) {
        #pragma unroll
        for (int h = 0; h < 4; ++h)
            *(short8*)&As[arow0 * 72 + aseg0 + h * 8] = *(const short8*)(pa + h * 8);
        *(short8*)&Bs[brow * 72 + bseg]     = *(const short8*)pw;
        *(short8*)&Bs[brow * 72 + bseg + 8] = *(const short8*)(pw + 8);
        pa += 64; pw += 64;
        __syncthreads();
        short8 a0[2], a1[2];
        #pragma unroll
        for (int i = 0; i < 2; ++i) {
            int row = w * 32 + i * 16 + ln;
            a0[i] = *(const short8*)&As[row * 72 + q * 8];
            a1[i] = *(const short8*)&As[row * 72 + 32 + q * 8];
        }
        #pragma unroll
        for (int j = 0; j < 4; ++j) {
            short8 bf0 = *(const short8*)&Bs[(j * 16 + ln) * 72 + q * 8];
            short8 bf1 = *(const short8*)&Bs[(j * 16 + ln) * 72 + 32 + q * 8];
            #pragma unroll
            for (int i = 0; i < 2; ++i) {
                acc[i][j] = __builtin_amdgcn_mfma_f32_16x16x32_bf16(a0[i], bf0, acc[i][j], 0, 0, 0);
                acc[i][j] = __builtin_amdgcn_mfma_f32_16x16x32_bf16(a1[i], bf1, acc[i][j], 0, 0, 0);
            }
        }
        __syncthreads();
    }
    #pragma unroll
    for (int i = 0; i < 2; ++i)
        #pragma unroll
        for (int j = 0; j < 4; ++j) {
            int nn = n0 + j * 16 + ln;
            #pragma unroll
            for (int r = 0; r < 4; ++r) {
                int m = m0 + w * 32 + i * 16 + q * 4 + r;
                Cbf[(size_t)m * N + nn] = f2bf(acc[i][j][r]);
            }
        }
}

// ---------------- dbl GEMM (N=48) + fused dt projection, batched pair ----------------
// Computes dbl[m,0..48] (fp32 out, needed by scans) and dt[m,d] = softplus(
// dbl[m,:16] @ dtw[d] + dtb[d]) -> bf16, in the same launch via LDS round-trip.
__global__ __launch_bounds__(256) void k_dbldt(
        const unsigned short* __restrict__ A0, const unsigned short* __restrict__ A1,
        const unsigned short* __restrict__ W0, const unsigned short* __restrict__ W1,
        const float* __restrict__ dtw0, const float* __restrict__ dtw1,
        const float* __restrict__ dtb0, const float* __restrict__ dtb1,
        float* __restrict__ Cf0, float* __restrict__ Cf1,
        unsigned short* __restrict__ dt0, unsigned short* __restrict__ dt1) {
    __shared__ __align__(16) unsigned short As[64 * 72];
    __shared__ __align__(16) unsigned short Bs[64 * 72];
    __shared__ float dblS[64 * 49];
    const int N = 48, K = 512;
    int p = blockIdx.z;
    const unsigned short* A = p ? A1 : A0;
    const unsigned short* W = p ? W1 : W0;
    const float* dtw = p ? dtw1 : dtw0;
    const float* dtb = p ? dtb1 : dtb0;
    float* Cf = p ? Cf1 : Cf0;
    unsigned short* dt = p ? dt1 : dt0;
    int tid = threadIdx.x;
    int m0 = blockIdx.y * 64;
    int w = tid >> 6, lane = tid & 63;
    int q = lane >> 4, ln = lane & 15;
    int srow = tid >> 2;
    int sseg = (tid & 3) * 16;

    const unsigned short* pa = A + (size_t)(m0 + srow) * K + sseg;
    const unsigned short* pw = W + (size_t)srow * K + sseg;
    bool nOK = (srow < N);

    f32x4 acc[4];
    #pragma unroll
    for (int j = 0; j < 4; ++j) acc[j] = (f32x4)(0.f);

    for (int k0 = 0; k0 < K; k0 += 64) {
        *(short8*)&As[srow * 72 + sseg]     = *(const short8*)pa;
        *(short8*)&As[srow * 72 + sseg + 8] = *(const short8*)(pa + 8);
        short8 b0 = (short8)(0), b1 = (short8)(0);
        if (nOK) { b0 = *(const short8*)pw; b1 = *(const short8*)(pw + 8); }
        *(short8*)&Bs[srow * 72 + sseg] = b0;
        *(short8*)&Bs[srow * 72 + sseg + 8] = b1;
        pa += 64; pw += 64;
        __syncthreads();
        short8 af0 = *(const short8*)&As[(w * 16 + ln) * 72 + q * 8];
        short8 af1 = *(const short8*)&As[(w * 16 + ln) * 72 + 32 + q * 8];
        #pragma unroll
        for (int j = 0; j < 4; ++j) {
            short8 bf0 = *(const short8*)&Bs[(j * 16 + ln) * 72 + q * 8];
            short8 bf1 = *(const short8*)&Bs[(j * 16 + ln) * 72 + 32 + q * 8];
            acc[j] = __builtin_amdgcn_mfma_f32_16x16x32_bf16(af0, bf0, acc[j], 0, 0, 0);
            acc[j] = __builtin_amdgcn_mfma_f32_16x16x32_bf16(af1, bf1, acc[j], 0, 0, 0);
        }
        __syncthreads();
    }
    // epilogue: write dbl to global + LDS tile
    #pragma unroll
    for (int j = 0; j < 4; ++j) {
        int nn = j * 16 + ln;
        if (nn < N) {
            #pragma unroll
            for (int r = 0; r < 4; ++r) {
                int lm = w * 16 + q * 4 + r;
                float v = acc[j][r];
                Cf[(size_t)(m0 + lm) * N + nn] = v;
                dblS[lm * 49 + nn] = v;
            }
        }
    }
    __syncthreads();
    // fused dtproj: thread owns d0 = tid*2, d0+1; sweeps the 64 rows
    {
        int d0 = tid * 2;
        float4 wA0 = *(const float4*)(dtw + d0 * 16);
        float4 wA1 = *(const float4*)(dtw + d0 * 16 + 4);
        float4 wA2 = *(const float4*)(dtw + d0 * 16 + 8);
        float4 wA3 = *(const float4*)(dtw + d0 * 16 + 12);
        float4 wB0 = *(const float4*)(dtw + d0 * 16 + 16);
        float4 wB1 = *(const float4*)(dtw + d0 * 16 + 20);
        float4 wB2 = *(const float4*)(dtw + d0 * 16 + 24);
        float4 wB3 = *(const float4*)(dtw + d0 * 16 + 28);
        float bA = dtb[d0], bB = dtb[d0 + 1];
        for (int r = 0; r < 64; ++r) {
            const float* row = &dblS[r * 49];
            float sA = bA, sB = bB;
            #pragma unroll
            for (int j = 0; j < 4; ++j) {
                float v = row[j];
                sA = fmaf(v, (&wA0.x)[j], sA);
                sB = fmaf(v, (&wB0.x)[j], sB);
            }
            #pragma unroll
            for (int j = 0; j < 4; ++j) {
                float v = row[4 + j];
                sA = fmaf(v, (&wA1.x)[j], sA);
                sB = fmaf(v, (&wB1.x)[j], sB);
            }
            #pragma unroll
            for (int j = 0; j < 4; ++j) {
                float v = row[8 + j];
                sA = fmaf(v, (&wA2.x)[j], sA);
                sB = fmaf(v, (&wB2.x)[j], sB);
            }
            #pragma unroll
            for (int j = 0; j < 4; ++j) {
                float v = row[12 + j];
                sA = fmaf(v, (&wA3.x)[j], sA);
                sB = fmaf(v, (&wB3.x)[j], sB);
            }
            float spA = fmaxf(sA, 0.f) + log1pf(__expf(-fabsf(sA)));
            float spB = fmaxf(sB, 0.f) + log1pf(__expf(-fabsf(sB)));
            ushort2 o; o.x = f2bf(spA); o.y = f2bf(spB);
            *(ushort2*)&dt[(size_t)(m0 + r) * 512 + d0] = o;
        }
    }
}

// ---------------- final GEMM with comb fused into A-staging ----------------
__global__ __launch_bounds__(256) void k_gemm_comb(const unsigned short* __restrict__ wbuf,
                                                   const unsigned short* __restrict__ mof,
                                                   const unsigned short* __restrict__ mob,
                                                   const unsigned short* __restrict__ W,
                                                   const float* __restrict__ bias,
                                                   const float* __restrict__ resid,
                                                   float* __restrict__ Cf,
                                                   int N, int K) {
    __shared__ __align__(16) unsigned short As[64 * 72];
    __shared__ __align__(16) unsigned short Bs[64 * 72];
    int tid = threadIdx.x;
    int m0 = blockIdx.y * 64, n0 = blockIdx.x * 64;
    int w = tid >> 6, lane = tid & 63;
    int q = lane >> 4, ln = lane & 15;
    int srow = tid >> 2;
    int sseg = (tid & 3) * 16;

    int mLog = m0 + srow;
    int mFlip = mLog ^ (C_LEN - 1);
    int nIdx = n0 + srow;
    const unsigned short* pw = W + (size_t)nIdx * K + sseg;
    bool nOK = (nIdx < N);

    f32x4 acc[4];
    #pragma unroll
    for (int j = 0; j < 4; ++j) acc[j] = (f32x4)(0.f);

    for (int k0 = 0; k0 < K; k0 += 64) {
        size_t off  = (size_t)mLog * 256 + k0 + sseg;
        size_t offb = (size_t)mFlip * 256 + k0 + sseg;
        #pragma unroll
        for (int h = 0; h < 2; ++h) {
            short8 aw = *(const short8*)(wbuf + off + h * 8);
            short8 af = *(const short8*)(mof + off + h * 8);
            short8 ab = *(const short8*)(mob + offb + h * 8);
            short8 av;
            #pragma unroll
            for (int j = 0; j < 8; ++j)
                av[j] = (short)f2bf(bf2f((unsigned short)aw[j]) *
                                    (bf2f((unsigned short)af[j]) + bf2f((unsigned short)ab[j])));
            *(short8*)&As[srow * 72 + sseg + h * 8] = av;
        }
        short8 b0 = (short8)(0), b1 = (short8)(0);
        if (nOK) { b0 = *(const short8*)pw; b1 = *(const short8*)(pw + 8); }
        *(short8*)&Bs[srow * 72 + sseg] = b0;
        *(short8*)&Bs[srow * 72 + sseg + 8] = b1;
        pw += 64;
        __syncthreads();
        short8 af0 = *(const short8*)&As[(w * 16 + ln) * 72 + q * 8];
        short8 af1 = *(const short8*)&As[(w * 16 + ln) * 72 + 32 + q * 8];
        #pragma unroll
        for (int j = 0; j < 4; ++j) {
            short8 bf0 = *(const short8*)&Bs[(j * 16 + ln) * 72 + q * 8];
            short8 bf1 = *(const short8*)&Bs[(j * 16 + ln) * 72 + 32 + q * 8];
            acc[j] = __builtin_amdgcn_mfma_f32_16x16x32_bf16(af0, bf0, acc[j], 0, 0, 0);
            acc[j] = __builtin_amdgcn_mfma_f32_16x16x32_bf16(af1, bf1, acc[j], 0, 0, 0);
        }
        __syncthreads();
    }
    #pragma unroll
    for (int j = 0; j < 4; ++j) {
        int nn = n0 + j * 16 + ln;
        if (nn < N) {
            float bsv = bias[nn];
            #pragma unroll
            for (int r = 0; r < 4; ++r) {
                int m = m0 + w * 16 + q * 4 + r;
                Cf[(size_t)m * N + nn] = acc[j][r] + bsv + resid[(size_t)m * N + nn];
            }
        }
    }
}

// ---------------- causal depthwise conv (K=4) + silu, both blocks ----------------
__global__ __launch_bounds__(256) void k_conv(const unsigned short* __restrict__ xz0,
                                              const unsigned short* __restrict__ xz1,
                                              const float* __restrict__ cw0,
                                              const float* __restrict__ cw1,
                                              const float* __restrict__ cb0,
                                              const float* __restrict__ cb1,
                                              unsigned short* __restrict__ xc0,
                                              unsigned short* __restrict__ xc1) {
    int pz = blockIdx.z;
    const unsigned short* xz = pz ? xz1 : xz0;
    const float* cw = pz ? cw1 : cw0;
    const float* cb = pz ? cb1 : cb0;
    unsigned short* xconv_bf = pz ? xc1 : xc0;
    int d = blockIdx.x * 256 + threadIdx.x;
    int by = blockIdx.y;
    int b = by >> 6, c0 = (by & 63) * 16;
    float4 cwv = *(const float4*)(cw + d * 4);
    float bias = cb[d];
    const unsigned short* base = xz + (size_t)(b * C_LEN) * 1024 + d;
    float w0 = 0.f, w1 = 0.f, w2 = 0.f;
    if (c0) {
        w0 = bf2f(base[(size_t)(c0 - 3) * 1024]);
        w1 = bf2f(base[(size_t)(c0 - 2) * 1024]);
        w2 = bf2f(base[(size_t)(c0 - 1) * 1024]);
    }
    unsigned short* out = xconv_bf + (size_t)(b * C_LEN + c0) * 512 + d;
    #pragma unroll
    for (int i = 0; i < 16; ++i) {
        float cur = bf2f(base[(size_t)(c0 + i) * 1024]);
        float acc = bias;
        acc = fmaf(cwv.x, w0, acc);
        acc = fmaf(cwv.y, w1, acc);
        acc = fmaf(cwv.z, w2, acc);
        acc = fmaf(cwv.w, cur, acc);
        out[(size_t)i * 512] = f2bf(siluf(acc));
        w0 = w1; w1 = w2; w2 = cur;
    }
}

// ---------------- scan pass 1: local chunk scan (dt bf16) ----------------
__global__ __launch_bounds__(256) void k_scan1(const unsigned short* __restrict__ dt0,
                                               const unsigned short* __restrict__ dt1,
                                               const unsigned short* __restrict__ xc0,
                                               const unsigned short* __restrict__ xc1,
                                               const float* __restrict__ dblA,
                                               const float* __restrict__ dblB,
                                               const float* __restrict__ alog0,
                                               const float* __restrict__ alog1,
                                               float* __restrict__ hfin0,
                                               float* __restrict__ hfin1,
                                               float* __restrict__ Pfin0,
                                               float* __restrict__ Pfin1) {
    int z = blockIdx.z;
    int b = z & 3, p = z >> 2;
    const unsigned short* dt = p ? dt1 : dt0;
    const unsigned short* xconv_bf = p ? xc1 : xc0;
    const float* dbl = p ? dblB : dblA;
    const float* A_log = p ? alog1 : alog0;
    float* hfin = p ? hfin1 : hfin0;
    float* Pfin = p ? Pfin1 : Pfin0;
    int tid = threadIdx.x;
    int nh = tid & 1, dl = tid >> 1;
    int k = blockIdx.x, dg = blockIdx.y;
    int d = dg * 128 + dl;
    float4 al0 = *(const float4*)&A_log[d * 16 + nh * 8];
    float4 al1 = *(const float4*)&A_log[d * 16 + nh * 8 + 4];
    float Ac[8] = {-__expf(al0.x), -__expf(al0.y), -__expf(al0.z), -__expf(al0.w),
                   -__expf(al1.x), -__expf(al1.y), -__expf(al1.z), -__expf(al1.w)};
    size_t r0 = (size_t)(b * C_LEN + k * CHUNK);
    const unsigned short* pdt = dt + r0 * 512 + d;
    const unsigned short* pxv = xconv_bf + r0 * 512 + d;
    const float* pB  = dbl + r0 * 48 + 16 + nh * 8;
    float h[8] = {0.f, 0.f, 0.f, 0.f, 0.f, 0.f, 0.f, 0.f};
    float sdt = 0.f;
    #pragma unroll 8
    for (int c = 0; c < CHUNK; ++c) {
        float dtv = bf2f(*pdt);
        float xv  = bf2f(*pxv);
        float4 B0 = *(const float4*)pB;
        float4 B1 = *(const float4*)(pB + 4);
        float dx = dtv * xv;
        float Bv[8] = {B0.x, B0.y, B0.z, B0.w, B1.x, B1.y, B1.z, B1.w};
        #pragma unroll
        for (int j = 0; j < 8; ++j)
            h[j] = fmaf(__expf(dtv * Ac[j]), h[j], dx * Bv[j]);
        sdt += dtv;
        pdt += 512; pxv += 512; pB += 48;
    }
    size_t idx = ((size_t)(b * NCHUNK + k) * 512 + d) * 16 + nh * 8;
    *(float4*)&hfin[idx]     = make_float4(h[0], h[1], h[2], h[3]);
    *(float4*)&hfin[idx + 4] = make_float4(h[4], h[5], h[6], h[7]);
    *(float4*)&Pfin[idx]     = make_float4(__expf(Ac[0] * sdt), __expf(Ac[1] * sdt),
                                           __expf(Ac[2] * sdt), __expf(Ac[3] * sdt));
    *(float4*)&Pfin[idx + 4] = make_float4(__expf(Ac[4] * sdt), __expf(Ac[5] * sdt),
                                           __expf(Ac[6] * sdt), __expf(Ac[7] * sdt));
}

// ---------------- scan pass 2: sequential carry combine (writes carries into Pfin) -------
__global__ __launch_bounds__(256) void k_scan2(const float* __restrict__ hfin0,
                                               const float* __restrict__ hfin1,
                                               float* __restrict__ Pfin0,
                                               float* __restrict__ Pfin1) {
    int tt = blockIdx.x * 256 + threadIdx.x;   // 0..65535
    int p = tt >> 15;
    int t = tt & 32767;
    const float* hfin = p ? hfin1 : hfin0;
    float* Pfin = p ? Pfin1 : Pfin0;
    int b = t >> 13;
    int dn = t & 8191;
    float carry = 0.f;
    #pragma unroll
    for (int k = 0; k < NCHUNK; ++k) {
        size_t idx = (size_t)(b * NCHUNK + k) * 8192 + dn;
        float pv = Pfin[idx];
        float hf = hfin[idx];
        Pfin[idx] = carry;
        carry = fmaf(pv, carry, hf);
    }
}

// ---------------- scan pass 3: replay with carry-in ----------------
__global__ __launch_bounds__(256) void k_scan3(const unsigned short* __restrict__ dt0,
                                               const unsigned short* __restrict__ dt1,
                                               const unsigned short* __restrict__ xc0,
                                               const unsigned short* __restrict__ xc1,
                                               const float* __restrict__ dblA,
                                               const float* __restrict__ dblB,
                                               const unsigned short* __restrict__ xz0,
                                               const unsigned short* __restrict__ xz1,
                                               const float* __restrict__ alog0,
                                               const float* __restrict__ alog1,
                                               const float* __restrict__ Dp0,
                                               const float* __restrict__ Dp1,
                                               const float* __restrict__ carry0,
                                               const float* __restrict__ carry1,
                                               unsigned short* __restrict__ g0,
                                               unsigned short* __restrict__ g1) {
    int z = blockIdx.z;
    int b = z & 3, p = z >> 2;
    const unsigned short* dt = p ? dt1 : dt0;
    const unsigned short* xconv_bf = p ? xc1 : xc0;
    const float* dbl = p ? dblB : dblA;
    const unsigned short* xz = p ? xz1 : xz0;
    const float* A_log = p ? alog1 : alog0;
    const float* Dp = p ? Dp1 : Dp0;
    const float* carryArr = p ? carry1 : carry0;
    unsigned short* gated_bf = p ? g1 : g0;
    int tid = threadIdx.x;
    int nh = tid & 1, dl = tid >> 1;
    int k = blockIdx.x, dg = blockIdx.y;
    int d = dg * 128 + dl;
    float4 al0 = *(const float4*)&A_log[d * 16 + nh * 8];
    float4 al1 = *(const float4*)&A_log[d * 16 + nh * 8 + 4];
    float Ac[8] = {-__expf(al0.x), -__expf(al0.y), -__expf(al0.z), -__expf(al0.w),
                   -__expf(al1.x), -__expf(al1.y), -__expf(al1.z), -__expf(al1.w)};
    float Dd = Dp[d];
    size_t idx = ((size_t)(b * NCHUNK + k) * 512 + d) * 16 + nh * 8;
    float4 h0 = *(const float4*)&carryArr[idx];
    float4 h1 = *(const float4*)&carryArr[idx + 4];
    float h[8] = {h0.x, h0.y, h0.z, h0.w, h1.x, h1.y, h1.z, h1.w};
    size_t r0 = (size_t)(b * C_LEN + k * CHUNK);
    const unsigned short* pdt = dt + r0 * 512 + d;
    const unsigned short* pxv = xconv_bf + r0 * 512 + d;
    const float* pB  = dbl + r0 * 48 + 16 + nh * 8;
    const float* pC  = dbl + r0 * 48 + 32 + nh * 8;
    const unsigned short* pz = xz + r0 * 1024 + 512 + d;
    unsigned short* pg = gated_bf + r0 * 512 + d;
    #pragma unroll 4
    for (int c = 0; c < CHUNK; ++c) {
        float dtv = bf2f(*pdt);
        float xv  = bf2f(*pxv);
        float4 B0 = *(const float4*)pB;
        float4 B1 = *(const float4*)(pB + 4);
        float4 C0 = *(const float4*)pC;
        float4 C1 = *(const float4*)(pC + 4);
        float dx = dtv * xv;
        float Bv[8] = {B0.x, B0.y, B0.z, B0.w, B1.x, B1.y, B1.z, B1.w};
        float Cv[8] = {C0.x, C0.y, C0.z, C0.w, C1.x, C1.y, C1.z, C1.w};
        float contrib = 0.f;
        #pragma unroll
        for (int j = 0; j < 8; ++j) {
            h[j] = fmaf(__expf(dtv * Ac[j]), h[j], dx * Bv[j]);
            contrib = fmaf(h[j], Cv[j], contrib);
        }
        contrib += __shfl_xor(contrib, 1, 64);
        if (nh == 0) {
            float y = contrib + xv * Dd;
            float zv = bf2f(*pz);
            *pg = f2bf(y * siluf(zv));
        }
        pdt += 512; pxv += 512; pB += 48; pC += 48; pz += 1024; pg += 512;
    }
}

// ---------------- postnorm both blocks: rmsnorm(mo)*w + u -> bf16 ----------------
__global__ __launch_bounds__(256) void k_postnorm(const unsigned short* __restrict__ mo0,
                                                  const unsigned short* __restrict__ mo1,
                                                  const float* __restrict__ w0,
                                                  const float* __restrict__ w1,
                                                  const unsigned short* __restrict__ u0,
                                                  const unsigned short* __restrict__ u1,
                                                  unsigned short* __restrict__ o0,
                                                  unsigned short* __restrict__ o1) {
    __shared__ float red[4];
    int p = blockIdx.y;
    const unsigned short* mo = p ? mo1 : mo0;
    const float* w = p ? w1 : w0;
    const unsigned short* u = p ? u1 : u0;
    unsigned short* out = p ? o1 : o0;
    int r = blockIdx.x, tid = threadIdx.x;
    float v = bf2f(mo[(size_t)r * 256 + tid]);
    float ss = v * v;
    #pragma unroll
    for (int off = 32; off; off >>= 1) ss += __shfl_xor(ss, off, 64);
    if ((tid & 63) == 0) red[tid >> 6] = ss;
    __syncthreads();
    float tot = red[0] + red[1] + red[2] + red[3];
    float rs = rsqrtf(tot * (1.f / 256.f) + 1e-5f);
    out[(size_t)r * 256 + tid] = f2bf(v * rs * w[tid] + bf2f(u[(size_t)r * 256 + tid]));
}

extern "C" void kernel_launch(void* const* d_in, const int* in_sizes, int n_in,
                              void* d_out, int out_size, void* d_ws, size_t ws_size,
                              hipStream_t stream) {
    const float* x          = (const float*)d_in[0];
    const float* W_in       = (const float*)d_in[1];
    const float* b_in       = (const float*)d_in[2];
    const float* W_wp       = (const float*)d_in[3];
    const float* b_wp       = (const float*)d_in[4];
    const float* W_fp       = (const float*)d_in[5];
    const float* b_fp       = (const float*)d_in[6];
    const float* W_bp       = (const float*)d_in[7];
    const float* b_bp       = (const float*)d_in[8];
    const float* W_out      = (const float*)d_in[9];
    const float* b_out      = (const float*)d_in[10];
    const float* norm_w_top = (const float*)d_in[11];
    const float* mamba_p[2][10];
    for (int p = 0; p < 2; ++p)
        for (int i = 0; i < 10; ++i)
            mamba_p[p][i] = (const float*)d_in[12 + p * 10 + i];

    // ---- workspace layout ----
    float* ws = (float*)d_ws;
    float* dblP[2]  = {ws + 0,       ws + 196608};
    float* hfinP[2] = {ws + 4587520, ws + 5636096};
    float* PfinP[2] = {ws + 6684672, ws + 7733248};
    unsigned short* dtsP[2] = {(unsigned short*)(ws + 393216),
                               (unsigned short*)(ws + 2490368)};

    unsigned short* us = (unsigned short*)(ws + 8781824);
    unsigned short* xn_bf   = us + 0;
    unsigned short* ssm_bf  = us + 524288;
    unsigned short* uf_bf   = us + 1572864;
    unsigned short* ub_bf   = us + 2621440;
    unsigned short* wbuf_bf = us + 3670016;
    unsigned short* xzP[2]  = {us + 4718592,  us + 8912896};
    unsigned short* xcP[2]  = {us + 13107200, us + 15204352};
    unsigned short* gP[2]   = {us + 17301504, us + 19398656};
    unsigned short* moP[2]  = {us + 21495808, us + 22544384};
    unsigned short* mof_bf  = us + 23592960;
    unsigned short* mob_bf  = us + 24641536;
    unsigned short* wb      = us + 25690112;
    unsigned short* wb_W_in  = wb + 0;
    unsigned short* wb_W_wp  = wb + 32768;
    unsigned short* wb_W_fp  = wb + 65536;
    unsigned short* wb_W_bp  = wb + 131072;
    unsigned short* wb_W_out = wb + 196608;
    unsigned short* wb_in[2]  = {wb + 229376, wb + 647168};
    unsigned short* wb_xp[2]  = {wb + 491520, wb + 909312};
    unsigned short* wb_outw[2]= {wb + 516096, wb + 933888};

    // 1. weights->bf16 + top rmsnorm
    WTab t;
    t.s[0] = W_in;            t.d[0] = wb_W_in;   t.n[0] = 32768;
    t.s[1] = W_wp;            t.d[1] = wb_W_wp;   t.n[1] = 32768;
    t.s[2] = W_fp;            t.d[2] = wb_W_fp;   t.n[2] = 65536;
    t.s[3] = W_bp;            t.d[3] = wb_W_bp;   t.n[3] = 65536;
    t.s[4] = W_out;           t.d[4] = wb_W_out;  t.n[4] = 32768;
    t.s[5] = mamba_p[0][0];   t.d[5] = wb_in[0];  t.n[5] = 262144;
    t.s[6] = mamba_p[0][3];   t.d[6] = wb_xp[0];  t.n[6] = 24576;
    t.s[7] = mamba_p[0][8];   t.d[7] = wb_outw[0];t.n[7] = 131072;
    t.s[8] = mamba_p[1][0];   t.d[8] = wb_in[1];  t.n[8] = 262144;
    t.s[9] = mamba_p[1][3];   t.d[9] = wb_xp[1];  t.n[9] = 24576;
    t.s[10]= mamba_p[1][8];   t.d[10]= wb_outw[1];t.n[10]= 131072;
    k_prep<<<dim3(256, 12), 256, 0, stream>>>(t, x, norm_w_top, xn_bf);

    // 2. ssm = xn @ W_in^T + b_in
    k_gemm_bf<<<dim3(4, 64), 256, 0, stream>>>(xn_bf, wb_W_in, b_in, ssm_bf, 256, 128);
    // 3. uf / ub / wbuf
    k_gemm3<<<dim3(4, 64, 3), 256, 0, stream>>>(xn_bf, ssm_bf, wb_W_fp, wb_W_bp, wb_W_wp,
                                                b_fp, b_bp, b_wp, uf_bf, ub_bf, wbuf_bf);
    // 4. xz = u @ in_w^T (K=256,N=1024), 128x64 tiles
    k_gemm128<<<dim3(16, 32, 2), 256, 0, stream>>>(uf_bf, ub_bf, wb_in[0], wb_in[1],
                                                   xzP[0], xzP[1], 1024, 256);
    // 5. conv + silu
    k_conv<<<dim3(2, 256, 2), 256, 0, stream>>>(xzP[0], xzP[1],
                                                mamba_p[0][1], mamba_p[1][1],
                                                mamba_p[0][2], mamba_p[1][2],
                                                xcP[0], xcP[1]);
    // 6. dbl GEMM + fused dtproj
    k_dbldt<<<dim3(1, 64, 2), 256, 0, stream>>>(xcP[0], xcP[1], wb_xp[0], wb_xp[1],
                                                mamba_p[0][4], mamba_p[1][4],
                                                mamba_p[0][5], mamba_p[1][5],
                                                dblP[0], dblP[1], dtsP[0], dtsP[1]);
    // 7. scan1 (local chunk scans)
    k_scan1<<<dim3(NCHUNK, 4, 8), 256, 0, stream>>>(dtsP[0], dtsP[1], xcP[0], xcP[1],
                                                    dblP[0], dblP[1],
                                                    mamba_p[0][6], mamba_p[1][6],
                                                    hfinP[0], hfinP[1], PfinP[0], PfinP[1]);
    // 8. scan2 (carry combine)
    k_scan2<<<256, 256, 0, stream>>>(hfinP[0], hfinP[1], PfinP[0], PfinP[1]);
    // 9. scan3 (replay with carry-in)
    k_scan3<<<dim3(NCHUNK, 4, 8), 256, 0, stream>>>(dtsP[0], dtsP[1], xcP[0], xcP[1],
                                                    dblP[0], dblP[1], xzP[0], xzP[1],
                                                    mamba_p[0][6], mamba_p[1][6],
                                                    mamba_p[0][7], mamba_p[1][7],
                                                    PfinP[0], PfinP[1], gP[0], gP[1]);
    // 10. mo_raw = gated @ out_w^T (K=512,N=256), 128x64 tiles
    k_gemm128<<<dim3(4, 32, 2), 256, 0, stream>>>(gP[0], gP[1], wb_outw[0], wb_outw[1],
                                                  moP[0], moP[1], 256, 512);
    // 11. postnorm both
    k_postnorm<<<dim3(NROW, 2), 256, 0, stream>>>(moP[0], moP[1],
                                                  mamba_p[0][9], mamba_p[1][9],
                                                  uf_bf, ub_bf, mof_bf, mob_bf);
    // 12. out = [wbuf*(mof+flip(mob))] @ W_out^T + b_out + x
    k_gemm_comb<<<dim3(2, 64), 256, 0, stream>>>(wbuf_bf, mof_bf, mob_bf, wb_W_out, b_out,
                                                 x, (float*)d_out, 128, 256);
}

// Round 19
// 255.102 us; speedup vs baseline: 6.2837x; 1.0687x over previous
//
#include <hip/hip_runtime.h>
#include <math.h>

#define C_LEN 1024
#define NROW 4096
#define NCHUNK 32
#define CHUNK 32

typedef __attribute__((ext_vector_type(8))) short short8;
typedef __attribute__((ext_vector_type(4))) float f32x4;

__device__ __forceinline__ float siluf(float x) { return x / (1.f + __expf(-x)); }

__device__ __forceinline__ unsigned short f2bf(float f) {
    unsigned u = __builtin_bit_cast(unsigned, f);
    unsigned r = (u + 0x7FFFu + ((u >> 16) & 1u)) >> 16;
    return (unsigned short)r;
}
__device__ __forceinline__ float bf2f(unsigned short v) {
    unsigned u = ((unsigned)v) << 16;
    return __builtin_bit_cast(float, u);
}

// ---------------- prep: weight fp32->bf16 (segs 0..10) + top rmsnorm (seg 11) ----------
struct WTab {
    const float* s[11];
    unsigned short* d[11];
    int n[11];
};
__global__ __launch_bounds__(256) void k_prep(WTab t, const float* __restrict__ x,
                                              const float* __restrict__ nw,
                                              unsigned short* __restrict__ xn_bf) {
    int seg = blockIdx.y;
    if (seg < 11) {
        int n = t.n[seg];
        int i = (blockIdx.x * 256 + threadIdx.x) * 4;
        if (i < n) {
            float4 v = *(const float4*)(t.s[seg] + i);
            unsigned short* o = t.d[seg] + i;
            o[0] = f2bf(v.x); o[1] = f2bf(v.y); o[2] = f2bf(v.z); o[3] = f2bf(v.w);
        }
    } else {
        int wave = threadIdx.x >> 6, lane = threadIdx.x & 63;
        #pragma unroll
        for (int it = 0; it < 4; ++it) {
            int row = blockIdx.x * 16 + it * 4 + wave;
            float2 v = ((const float2*)(x + (size_t)row * 128))[lane];
            float ss = v.x * v.x + v.y * v.y;
            #pragma unroll
            for (int off = 32; off; off >>= 1) ss += __shfl_xor(ss, off, 64);
            float rs = rsqrtf(ss * (1.f / 128.f) + 1e-5f);
            float2 wv = ((const float2*)nw)[lane];
            ushort2 o;
            o.x = f2bf(v.x * rs * wv.x);
            o.y = f2bf(v.y * rs * wv.y);
            ((ushort2*)(xn_bf + (size_t)row * 128))[lane] = o;
        }
    }
}

// ---------------- 64x64 bf16 GEMM (step 2): bf16 out + bias ----------------
__global__ __launch_bounds__(256) void k_gemm_bf(const unsigned short* __restrict__ A,
                                                 const unsigned short* __restrict__ W,
                                                 const float* __restrict__ bias,
                                                 unsigned short* __restrict__ Cbf,
                                                 int N, int K) {
    __shared__ __align__(16) unsigned short As[64 * 72];
    __shared__ __align__(16) unsigned short Bs[64 * 72];
    int tid = threadIdx.x;
    int m0 = blockIdx.y * 64, n0 = blockIdx.x * 64;
    int w = tid >> 6, lane = tid & 63;
    int q = lane >> 4, ln = lane & 15;
    int srow = tid >> 2;
    int sseg = (tid & 3) * 16;

    const unsigned short* pa = A + (size_t)(m0 + srow) * K + sseg;
    const unsigned short* pw = W + (size_t)(n0 + srow) * K + sseg;

    f32x4 acc[4];
    #pragma unroll
    for (int j = 0; j < 4; ++j) acc[j] = (f32x4)(0.f);

    for (int k0 = 0; k0 < K; k0 += 64) {
        *(short8*)&As[srow * 72 + sseg]     = *(const short8*)pa;
        *(short8*)&As[srow * 72 + sseg + 8] = *(const short8*)(pa + 8);
        *(short8*)&Bs[srow * 72 + sseg]     = *(const short8*)pw;
        *(short8*)&Bs[srow * 72 + sseg + 8] = *(const short8*)(pw + 8);
        pa += 64; pw += 64;
        __syncthreads();
        short8 af0 = *(const short8*)&As[(w * 16 + ln) * 72 + q * 8];
        short8 af1 = *(const short8*)&As[(w * 16 + ln) * 72 + 32 + q * 8];
        #pragma unroll
        for (int j = 0; j < 4; ++j) {
            short8 bf0 = *(const short8*)&Bs[(j * 16 + ln) * 72 + q * 8];
            short8 bf1 = *(const short8*)&Bs[(j * 16 + ln) * 72 + 32 + q * 8];
            acc[j] = __builtin_amdgcn_mfma_f32_16x16x32_bf16(af0, bf0, acc[j], 0, 0, 0);
            acc[j] = __builtin_amdgcn_mfma_f32_16x16x32_bf16(af1, bf1, acc[j], 0, 0, 0);
        }
        __syncthreads();
    }
    #pragma unroll
    for (int j = 0; j < 4; ++j) {
        int nn = n0 + j * 16 + ln;
        float bsv = bias[nn];
        #pragma unroll
        for (int r = 0; r < 4; ++r) {
            int m = m0 + w * 16 + q * 4 + r;
            Cbf[(size_t)m * N + nn] = f2bf(acc[j][r] + bsv);
        }
    }
}

// ---------------- 3-way GEMM: z=0 uf (W_fp), z=1 ub (W_bp, flip), z=2 wbuf (W_wp, silu) ----
__global__ __launch_bounds__(256) void k_gemm3(
        const unsigned short* __restrict__ xn, const unsigned short* __restrict__ ssm,
        const unsigned short* __restrict__ Wfp, const unsigned short* __restrict__ Wbp,
        const unsigned short* __restrict__ Wwp,
        const float* __restrict__ bfp, const float* __restrict__ bbp,
        const float* __restrict__ bwp,
        unsigned short* __restrict__ uf, unsigned short* __restrict__ ub,
        unsigned short* __restrict__ wbuf) {
    __shared__ __align__(16) unsigned short As[64 * 72];
    __shared__ __align__(16) unsigned short Bs[64 * 72];
    int z = blockIdx.z;
    const unsigned short* A = (z == 2) ? xn : ssm;
    const unsigned short* W = (z == 0) ? Wfp : (z == 1) ? Wbp : Wwp;
    const float* bias = (z == 0) ? bfp : (z == 1) ? bbp : bwp;
    unsigned short* C = (z == 0) ? uf : (z == 1) ? ub : wbuf;
    int K = (z == 2) ? 128 : 256;
    int tid = threadIdx.x;
    int m0 = blockIdx.y * 64, n0 = blockIdx.x * 64;
    int w = tid >> 6, lane = tid & 63;
    int q = lane >> 4, ln = lane & 15;
    int srow = tid >> 2;
    int sseg = (tid & 3) * 16;

    int mLog = m0 + srow;
    int mPhys = (z == 1) ? (mLog ^ (C_LEN - 1)) : mLog;
    const unsigned short* pa = A + (size_t)mPhys * K + sseg;
    const unsigned short* pw = W + (size_t)(n0 + srow) * K + sseg;

    f32x4 acc[4];
    #pragma unroll
    for (int j = 0; j < 4; ++j) acc[j] = (f32x4)(0.f);

    for (int k0 = 0; k0 < K; k0 += 64) {
        *(short8*)&As[srow * 72 + sseg]     = *(const short8*)pa;
        *(short8*)&As[srow * 72 + sseg + 8] = *(const short8*)(pa + 8);
        *(short8*)&Bs[srow * 72 + sseg]     = *(const short8*)pw;
        *(short8*)&Bs[srow * 72 + sseg + 8] = *(const short8*)(pw + 8);
        pa += 64; pw += 64;
        __syncthreads();
        short8 af0 = *(const short8*)&As[(w * 16 + ln) * 72 + q * 8];
        short8 af1 = *(const short8*)&As[(w * 16 + ln) * 72 + 32 + q * 8];
        #pragma unroll
        for (int j = 0; j < 4; ++j) {
            short8 bf0 = *(const short8*)&Bs[(j * 16 + ln) * 72 + q * 8];
            short8 bf1 = *(const short8*)&Bs[(j * 16 + ln) * 72 + 32 + q * 8];
            acc[j] = __builtin_amdgcn_mfma_f32_16x16x32_bf16(af0, bf0, acc[j], 0, 0, 0);
            acc[j] = __builtin_amdgcn_mfma_f32_16x16x32_bf16(af1, bf1, acc[j], 0, 0, 0);
        }
        __syncthreads();
    }
    #pragma unroll
    for (int j = 0; j < 4; ++j) {
        int nn = n0 + j * 16 + ln;
        float bsv = bias[nn];
        #pragma unroll
        for (int r = 0; r < 4; ++r) {
            int m = m0 + w * 16 + q * 4 + r;
            float v = acc[j][r] + bsv;
            if (z == 2) v = siluf(v);
            C[(size_t)m * 256 + nn] = f2bf(v);
        }
    }
}

// ---------------- 128x64 bf16 GEMM, batched pair (big stages: xz, mo) ----------------
__global__ __launch_bounds__(256) void k_gemm128(
        const unsigned short* __restrict__ A0, const unsigned short* __restrict__ A1,
        const unsigned short* __restrict__ W0, const unsigned short* __restrict__ W1,
        unsigned short* __restrict__ Cb0, unsigned short* __restrict__ Cb1,
        int N, int K) {
    __shared__ __align__(16) unsigned short As[128 * 72];
    __shared__ __align__(16) unsigned short Bs[64 * 72];
    int p = blockIdx.z;
    const unsigned short* A = p ? A1 : A0;
    const unsigned short* W = p ? W1 : W0;
    unsigned short* Cbf = p ? Cb1 : Cb0;
    int tid = threadIdx.x;
    int m0 = blockIdx.y * 128, n0 = blockIdx.x * 64;
    int w = tid >> 6, lane = tid & 63;
    int q = lane >> 4, ln = lane & 15;

    int arow0 = tid >> 1;
    int aseg0 = (tid & 1) * 32;
    int brow = tid >> 2, bseg = (tid & 3) * 16;
    const unsigned short* pa = A + (size_t)(m0 + arow0) * K + aseg0;
    const unsigned short* pw = W + (size_t)(n0 + brow) * K + bseg;

    f32x4 acc[2][4];
    #pragma unroll
    for (int i = 0; i < 2; ++i)
        #pragma unroll
        for (int j = 0; j < 4; ++j) acc[i][j] = (f32x4)(0.f);

    for (int k0 = 0; k0 < K; k0 += 64) {
        #pragma unroll
        for (int h = 0; h < 4; ++h)
            *(short8*)&As[arow0 * 72 + aseg0 + h * 8] = *(const short8*)(pa + h * 8);
        *(short8*)&Bs[brow * 72 + bseg]     = *(const short8*)pw;
        *(short8*)&Bs[brow * 72 + bseg + 8] = *(const short8*)(pw + 8);
        pa += 64; pw += 64;
        __syncthreads();
        short8 a0[2], a1[2];
        #pragma unroll
        for (int i = 0; i < 2; ++i) {
            int row = w * 32 + i * 16 + ln;
            a0[i] = *(const short8*)&As[row * 72 + q * 8];
            a1[i] = *(const short8*)&As[row * 72 + 32 + q * 8];
        }
        #pragma unroll
        for (int j = 0; j < 4; ++j) {
            short8 bf0 = *(const short8*)&Bs[(j * 16 + ln) * 72 + q * 8];
            short8 bf1 = *(const short8*)&Bs[(j * 16 + ln) * 72 + 32 + q * 8];
            #pragma unroll
            for (int i = 0; i < 2; ++i) {
                acc[i][j] = __builtin_amdgcn_mfma_f32_16x16x32_bf16(a0[i], bf0, acc[i][j], 0, 0, 0);
                acc[i][j] = __builtin_amdgcn_mfma_f32_16x16x32_bf16(a1[i], bf1, acc[i][j], 0, 0, 0);
            }
        }
        __syncthreads();
    }
    #pragma unroll
    for (int i = 0; i < 2; ++i)
        #pragma unroll
        for (int j = 0; j < 4; ++j) {
            int nn = n0 + j * 16 + ln;
            #pragma unroll
            for (int r = 0; r < 4; ++r) {
                int m = m0 + w * 32 + i * 16 + q * 4 + r;
                Cbf[(size_t)m * N + nn] = f2bf(acc[i][j][r]);
            }
        }
}

// ---------------- 64x64 pair GEMM, fp32 out (dbl stage) ----------------
__global__ __launch_bounds__(256) void k_gemm2f(
        const unsigned short* __restrict__ A0, const unsigned short* __restrict__ A1,
        const unsigned short* __restrict__ W0, const unsigned short* __restrict__ W1,
        float* __restrict__ Cf0, float* __restrict__ Cf1,
        int N, int K) {
    __shared__ __align__(16) unsigned short As[64 * 72];
    __shared__ __align__(16) unsigned short Bs[64 * 72];
    int p = blockIdx.z;
    const unsigned short* A = p ? A1 : A0;
    const unsigned short* W = p ? W1 : W0;
    float* Cf = p ? Cf1 : Cf0;
    int tid = threadIdx.x;
    int m0 = blockIdx.y * 64, n0 = blockIdx.x * 64;
    int w = tid >> 6, lane = tid & 63;
    int q = lane >> 4, ln = lane & 15;
    int srow = tid >> 2;
    int sseg = (tid & 3) * 16;

    const unsigned short* pa = A + (size_t)(m0 + srow) * K + sseg;
    int nIdx = n0 + srow;
    const unsigned short* pw = W + (size_t)nIdx * K + sseg;
    bool nOK = (nIdx < N);

    f32x4 acc[4];
    #pragma unroll
    for (int j = 0; j < 4; ++j) acc[j] = (f32x4)(0.f);

    for (int k0 = 0; k0 < K; k0 += 64) {
        *(short8*)&As[srow * 72 + sseg]     = *(const short8*)pa;
        *(short8*)&As[srow * 72 + sseg + 8] = *(const short8*)(pa + 8);
        short8 b0 = (short8)(0), b1 = (short8)(0);
        if (nOK) { b0 = *(const short8*)pw; b1 = *(const short8*)(pw + 8); }
        *(short8*)&Bs[srow * 72 + sseg] = b0;
        *(short8*)&Bs[srow * 72 + sseg + 8] = b1;
        pa += 64; pw += 64;
        __syncthreads();
        short8 af0 = *(const short8*)&As[(w * 16 + ln) * 72 + q * 8];
        short8 af1 = *(const short8*)&As[(w * 16 + ln) * 72 + 32 + q * 8];
        #pragma unroll
        for (int j = 0; j < 4; ++j) {
            short8 bf0 = *(const short8*)&Bs[(j * 16 + ln) * 72 + q * 8];
            short8 bf1 = *(const short8*)&Bs[(j * 16 + ln) * 72 + 32 + q * 8];
            acc[j] = __builtin_amdgcn_mfma_f32_16x16x32_bf16(af0, bf0, acc[j], 0, 0, 0);
            acc[j] = __builtin_amdgcn_mfma_f32_16x16x32_bf16(af1, bf1, acc[j], 0, 0, 0);
        }
        __syncthreads();
    }
    #pragma unroll
    for (int j = 0; j < 4; ++j) {
        int nn = n0 + j * 16 + ln;
        if (nn < N) {
            #pragma unroll
            for (int r = 0; r < 4; ++r) {
                int m = m0 + w * 16 + q * 4 + r;
                Cf[(size_t)m * N + nn] = acc[j][r];
            }
        }
    }
}

// ---------------- final GEMM with comb fused into A-staging ----------------
__global__ __launch_bounds__(256) void k_gemm_comb(const unsigned short* __restrict__ wbuf,
                                                   const unsigned short* __restrict__ mof,
                                                   const unsigned short* __restrict__ mob,
                                                   const unsigned short* __restrict__ W,
                                                   const float* __restrict__ bias,
                                                   const float* __restrict__ resid,
                                                   float* __restrict__ Cf,
                                                   int N, int K) {
    __shared__ __align__(16) unsigned short As[64 * 72];
    __shared__ __align__(16) unsigned short Bs[64 * 72];
    int tid = threadIdx.x;
    int m0 = blockIdx.y * 64, n0 = blockIdx.x * 64;
    int w = tid >> 6, lane = tid & 63;
    int q = lane >> 4, ln = lane & 15;
    int srow = tid >> 2;
    int sseg = (tid & 3) * 16;

    int mLog = m0 + srow;
    int mFlip = mLog ^ (C_LEN - 1);
    int nIdx = n0 + srow;
    const unsigned short* pw = W + (size_t)nIdx * K + sseg;
    bool nOK = (nIdx < N);

    f32x4 acc[4];
    #pragma unroll
    for (int j = 0; j < 4; ++j) acc[j] = (f32x4)(0.f);

    for (int k0 = 0; k0 < K; k0 += 64) {
        size_t off  = (size_t)mLog * 256 + k0 + sseg;
        size_t offb = (size_t)mFlip * 256 + k0 + sseg;
        #pragma unroll
        for (int h = 0; h < 2; ++h) {
            short8 aw = *(const short8*)(wbuf + off + h * 8);
            short8 af = *(const short8*)(mof + off + h * 8);
            short8 ab = *(const short8*)(mob + offb + h * 8);
            short8 av;
            #pragma unroll
            for (int j = 0; j < 8; ++j)
                av[j] = (short)f2bf(bf2f((unsigned short)aw[j]) *
                                    (bf2f((unsigned short)af[j]) + bf2f((unsigned short)ab[j])));
            *(short8*)&As[srow * 72 + sseg + h * 8] = av;
        }
        short8 b0 = (short8)(0), b1 = (short8)(0);
        if (nOK) { b0 = *(const short8*)pw; b1 = *(const short8*)(pw + 8); }
        *(short8*)&Bs[srow * 72 + sseg] = b0;
        *(short8*)&Bs[srow * 72 + sseg + 8] = b1;
        pw += 64;
        __syncthreads();
        short8 af0 = *(const short8*)&As[(w * 16 + ln) * 72 + q * 8];
        short8 af1 = *(const short8*)&As[(w * 16 + ln) * 72 + 32 + q * 8];
        #pragma unroll
        for (int j = 0; j < 4; ++j) {
            short8 bf0 = *(const short8*)&Bs[(j * 16 + ln) * 72 + q * 8];
            short8 bf1 = *(const short8*)&Bs[(j * 16 + ln) * 72 + 32 + q * 8];
            acc[j] = __builtin_amdgcn_mfma_f32_16x16x32_bf16(af0, bf0, acc[j], 0, 0, 0);
            acc[j] = __builtin_amdgcn_mfma_f32_16x16x32_bf16(af1, bf1, acc[j], 0, 0, 0);
        }
        __syncthreads();
    }
    #pragma unroll
    for (int j = 0; j < 4; ++j) {
        int nn = n0 + j * 16 + ln;
        if (nn < N) {
            float bsv = bias[nn];
            #pragma unroll
            for (int r = 0; r < 4; ++r) {
                int m = m0 + w * 16 + q * 4 + r;
                Cf[(size_t)m * N + nn] = acc[j][r] + bsv + resid[(size_t)m * N + nn];
            }
        }
    }
}

// ---------------- causal depthwise conv (K=4) + silu, both blocks ----------------
__global__ __launch_bounds__(256) void k_conv(const unsigned short* __restrict__ xz0,
                                              const unsigned short* __restrict__ xz1,
                                              const float* __restrict__ cw0,
                                              const float* __restrict__ cw1,
                                              const float* __restrict__ cb0,
                                              const float* __restrict__ cb1,
                                              unsigned short* __restrict__ xc0,
                                              unsigned short* __restrict__ xc1) {
    int pz = blockIdx.z;
    const unsigned short* xz = pz ? xz1 : xz0;
    const float* cw = pz ? cw1 : cw0;
    const float* cb = pz ? cb1 : cb0;
    unsigned short* xconv_bf = pz ? xc1 : xc0;
    int d = blockIdx.x * 256 + threadIdx.x;
    int by = blockIdx.y;
    int b = by >> 6, c0 = (by & 63) * 16;
    float4 cwv = *(const float4*)(cw + d * 4);
    float bias = cb[d];
    const unsigned short* base = xz + (size_t)(b * C_LEN) * 1024 + d;
    float w0 = 0.f, w1 = 0.f, w2 = 0.f;
    if (c0) {
        w0 = bf2f(base[(size_t)(c0 - 3) * 1024]);
        w1 = bf2f(base[(size_t)(c0 - 2) * 1024]);
        w2 = bf2f(base[(size_t)(c0 - 1) * 1024]);
    }
    unsigned short* out = xconv_bf + (size_t)(b * C_LEN + c0) * 512 + d;
    #pragma unroll
    for (int i = 0; i < 16; ++i) {
        float cur = bf2f(base[(size_t)(c0 + i) * 1024]);
        float acc = bias;
        acc = fmaf(cwv.x, w0, acc);
        acc = fmaf(cwv.y, w1, acc);
        acc = fmaf(cwv.z, w2, acc);
        acc = fmaf(cwv.w, cur, acc);
        out[(size_t)i * 512] = f2bf(siluf(acc));
        w0 = w1; w1 = w2; w2 = cur;
    }
}

// ---------------- dt projection -> bf16, 8 rows per thread, both blocks ----------------
__global__ __launch_bounds__(256) void k_dtproj(const float* __restrict__ dbl0,
                                                const float* __restrict__ dbl1,
                                                const float* __restrict__ dtw0,
                                                const float* __restrict__ dtw1,
                                                const float* __restrict__ dtb0,
                                                const float* __restrict__ dtb1,
                                                unsigned short* __restrict__ dt0,
                                                unsigned short* __restrict__ dt1) {
    int pz = blockIdx.z;
    const float* dbl = pz ? dbl1 : dbl0;
    const float* dtw = pz ? dtw1 : dtw0;
    const float* dtb = pz ? dtb1 : dtb0;
    unsigned short* dt = pz ? dt1 : dt0;
    int d = blockIdx.x * 256 + threadIdx.x;
    int r0 = blockIdx.y * 8;
    float4 w0 = *(const float4*)(dtw + d * 16);
    float4 w1 = *(const float4*)(dtw + d * 16 + 4);
    float4 w2 = *(const float4*)(dtw + d * 16 + 8);
    float4 w3 = *(const float4*)(dtw + d * 16 + 12);
    float bias = dtb[d];
    #pragma unroll
    for (int rr = 0; rr < 8; ++rr) {
        int r = r0 + rr;
        const float* row = dbl + (size_t)r * 48;
        float s = bias;
        s = fmaf(row[0], w0.x, s);  s = fmaf(row[1], w0.y, s);
        s = fmaf(row[2], w0.z, s);  s = fmaf(row[3], w0.w, s);
        s = fmaf(row[4], w1.x, s);  s = fmaf(row[5], w1.y, s);
        s = fmaf(row[6], w1.z, s);  s = fmaf(row[7], w1.w, s);
        s = fmaf(row[8], w2.x, s);  s = fmaf(row[9], w2.y, s);
        s = fmaf(row[10], w2.z, s); s = fmaf(row[11], w2.w, s);
        s = fmaf(row[12], w3.x, s); s = fmaf(row[13], w3.y, s);
        s = fmaf(row[14], w3.z, s); s = fmaf(row[15], w3.w, s);
        float sp = fmaxf(s, 0.f) + log1pf(__expf(-fabsf(s)));
        dt[(size_t)r * 512 + d] = f2bf(sp);
    }
}

// ---------------- scan pass 1: local chunk scan (dt bf16) ----------------
__global__ __launch_bounds__(256) void k_scan1(const unsigned short* __restrict__ dt0,
                                               const unsigned short* __restrict__ dt1,
                                               const unsigned short* __restrict__ xc0,
                                               const unsigned short* __restrict__ xc1,
                                               const float* __restrict__ dblA,
                                               const float* __restrict__ dblB,
                                               const float* __restrict__ alog0,
                                               const float* __restrict__ alog1,
                                               float* __restrict__ hfin0,
                                               float* __restrict__ hfin1,
                                               float* __restrict__ Pfin0,
                                               float* __restrict__ Pfin1) {
    int z = blockIdx.z;
    int b = z & 3, p = z >> 2;
    const unsigned short* dt = p ? dt1 : dt0;
    const unsigned short* xconv_bf = p ? xc1 : xc0;
    const float* dbl = p ? dblB : dblA;
    const float* A_log = p ? alog1 : alog0;
    float* hfin = p ? hfin1 : hfin0;
    float* Pfin = p ? Pfin1 : Pfin0;
    int tid = threadIdx.x;
    int nh = tid & 1, dl = tid >> 1;
    int k = blockIdx.x, dg = blockIdx.y;
    int d = dg * 128 + dl;
    float4 al0 = *(const float4*)&A_log[d * 16 + nh * 8];
    float4 al1 = *(const float4*)&A_log[d * 16 + nh * 8 + 4];
    float Ac[8] = {-__expf(al0.x), -__expf(al0.y), -__expf(al0.z), -__expf(al0.w),
                   -__expf(al1.x), -__expf(al1.y), -__expf(al1.z), -__expf(al1.w)};
    size_t r0 = (size_t)(b * C_LEN + k * CHUNK);
    const unsigned short* pdt = dt + r0 * 512 + d;
    const unsigned short* pxv = xconv_bf + r0 * 512 + d;
    const float* pB  = dbl + r0 * 48 + 16 + nh * 8;
    float h[8] = {0.f, 0.f, 0.f, 0.f, 0.f, 0.f, 0.f, 0.f};
    float sdt = 0.f;
    #pragma unroll 8
    for (int c = 0; c < CHUNK; ++c) {
        float dtv = bf2f(*pdt);
        float xv  = bf2f(*pxv);
        float4 B0 = *(const float4*)pB;
        float4 B1 = *(const float4*)(pB + 4);
        float dx = dtv * xv;
        float Bv[8] = {B0.x, B0.y, B0.z, B0.w, B1.x, B1.y, B1.z, B1.w};
        #pragma unroll
        for (int j = 0; j < 8; ++j)
            h[j] = fmaf(__expf(dtv * Ac[j]), h[j], dx * Bv[j]);
        sdt += dtv;
        pdt += 512; pxv += 512; pB += 48;
    }
    size_t idx = ((size_t)(b * NCHUNK + k) * 512 + d) * 16 + nh * 8;
    *(float4*)&hfin[idx]     = make_float4(h[0], h[1], h[2], h[3]);
    *(float4*)&hfin[idx + 4] = make_float4(h[4], h[5], h[6], h[7]);
    *(float4*)&Pfin[idx]     = make_float4(__expf(Ac[0] * sdt), __expf(Ac[1] * sdt),
                                           __expf(Ac[2] * sdt), __expf(Ac[3] * sdt));
    *(float4*)&Pfin[idx + 4] = make_float4(__expf(Ac[4] * sdt), __expf(Ac[5] * sdt),
                                           __expf(Ac[6] * sdt), __expf(Ac[7] * sdt));
}

// ---------------- scan pass 2: sequential carry combine (writes carries into Pfin) -------
__global__ __launch_bounds__(256) void k_scan2(const float* __restrict__ hfin0,
                                               const float* __restrict__ hfin1,
                                               float* __restrict__ Pfin0,
                                               float* __restrict__ Pfin1) {
    int tt = blockIdx.x * 256 + threadIdx.x;   // 0..65535
    int p = tt >> 15;
    int t = tt & 32767;
    const float* hfin = p ? hfin1 : hfin0;
    float* Pfin = p ? Pfin1 : Pfin0;
    int b = t >> 13;
    int dn = t & 8191;
    float carry = 0.f;
    #pragma unroll
    for (int k = 0; k < NCHUNK; ++k) {
        size_t idx = (size_t)(b * NCHUNK + k) * 8192 + dn;
        float pv = Pfin[idx];
        float hf = hfin[idx];
        Pfin[idx] = carry;
        carry = fmaf(pv, carry, hf);
    }
}

// ---------------- scan pass 3: replay with carry-in ----------------
__global__ __launch_bounds__(256) void k_scan3(const unsigned short* __restrict__ dt0,
                                               const unsigned short* __restrict__ dt1,
                                               const unsigned short* __restrict__ xc0,
                                               const unsigned short* __restrict__ xc1,
                                               const float* __restrict__ dblA,
                                               const float* __restrict__ dblB,
                                               const unsigned short* __restrict__ xz0,
                                               const unsigned short* __restrict__ xz1,
                                               const float* __restrict__ alog0,
                                               const float* __restrict__ alog1,
                                               const float* __restrict__ Dp0,
                                               const float* __restrict__ Dp1,
                                               const float* __restrict__ carry0,
                                               const float* __restrict__ carry1,
                                               unsigned short* __restrict__ g0,
                                               unsigned short* __restrict__ g1) {
    int z = blockIdx.z;
    int b = z & 3, p = z >> 2;
    const unsigned short* dt = p ? dt1 : dt0;
    const unsigned short* xconv_bf = p ? xc1 : xc0;
    const float* dbl = p ? dblB : dblA;
    const unsigned short* xz = p ? xz1 : xz0;
    const float* A_log = p ? alog1 : alog0;
    const float* Dp = p ? Dp1 : Dp0;
    const float* carryArr = p ? carry1 : carry0;
    unsigned short* gated_bf = p ? g1 : g0;
    int tid = threadIdx.x;
    int nh = tid & 1, dl = tid >> 1;
    int k = blockIdx.x, dg = blockIdx.y;
    int d = dg * 128 + dl;
    float4 al0 = *(const float4*)&A_log[d * 16 + nh * 8];
    float4 al1 = *(const float4*)&A_log[d * 16 + nh * 8 + 4];
    float Ac[8] = {-__expf(al0.x), -__expf(al0.y), -__expf(al0.z), -__expf(al0.w),
                   -__expf(al1.x), -__expf(al1.y), -__expf(al1.z), -__expf(al1.w)};
    float Dd = Dp[d];
    size_t idx = ((size_t)(b * NCHUNK + k) * 512 + d) * 16 + nh * 8;
    float4 h0 = *(const float4*)&carryArr[idx];
    float4 h1 = *(const float4*)&carryArr[idx + 4];
    float h[8] = {h0.x, h0.y, h0.z, h0.w, h1.x, h1.y, h1.z, h1.w};
    size_t r0 = (size_t)(b * C_LEN + k * CHUNK);
    const unsigned short* pdt = dt + r0 * 512 + d;
    const unsigned short* pxv = xconv_bf + r0 * 512 + d;
    const float* pB  = dbl + r0 * 48 + 16 + nh * 8;
    const float* pC  = dbl + r0 * 48 + 32 + nh * 8;
    const unsigned short* pz = xz + r0 * 1024 + 512 + d;
    unsigned short* pg = gated_bf + r0 * 512 + d;
    #pragma unroll 4
    for (int c = 0; c < CHUNK; ++c) {
        float dtv = bf2f(*pdt);
        float xv  = bf2f(*pxv);
        float4 B0 = *(const float4*)pB;
        float4 B1 = *(const float4*)(pB + 4);
        float4 C0 = *(const float4*)pC;
        float4 C1 = *(const float4*)(pC + 4);
        float dx = dtv * xv;
        float Bv[8] = {B0.x, B0.y, B0.z, B0.w, B1.x, B1.y, B1.z, B1.w};
        float Cv[8] = {C0.x, C0.y, C0.z, C0.w, C1.x, C1.y, C1.z, C1.w};
        float contrib = 0.f;
        #pragma unroll
        for (int j = 0; j < 8; ++j) {
            h[j] = fmaf(__expf(dtv * Ac[j]), h[j], dx * Bv[j]);
            contrib = fmaf(h[j], Cv[j], contrib);
        }
        contrib += __shfl_xor(contrib, 1, 64);
        if (nh == 0) {
            float y = contrib + xv * Dd;
            float zv = bf2f(*pz);
            *pg = f2bf(y * siluf(zv));
        }
        pdt += 512; pxv += 512; pB += 48; pC += 48; pz += 1024; pg += 512;
    }
}

// ---------------- postnorm both blocks: rmsnorm(mo)*w + u -> bf16 ----------------
__global__ __launch_bounds__(256) void k_postnorm(const unsigned short* __restrict__ mo0,
                                                  const unsigned short* __restrict__ mo1,
                                                  const float* __restrict__ w0,
                                                  const float* __restrict__ w1,
                                                  const unsigned short* __restrict__ u0,
                                                  const unsigned short* __restrict__ u1,
                                                  unsigned short* __restrict__ o0,
                                                  unsigned short* __restrict__ o1) {
    __shared__ float red[4];
    int p = blockIdx.y;
    const unsigned short* mo = p ? mo1 : mo0;
    const float* w = p ? w1 : w0;
    const unsigned short* u = p ? u1 : u0;
    unsigned short* out = p ? o1 : o0;
    int r = blockIdx.x, tid = threadIdx.x;
    float v = bf2f(mo[(size_t)r * 256 + tid]);
    float ss = v * v;
    #pragma unroll
    for (int off = 32; off; off >>= 1) ss += __shfl_xor(ss, off, 64);
    if ((tid & 63) == 0) red[tid >> 6] = ss;
    __syncthreads();
    float tot = red[0] + red[1] + red[2] + red[3];
    float rs = rsqrtf(tot * (1.f / 256.f) + 1e-5f);
    out[(size_t)r * 256 + tid] = f2bf(v * rs * w[tid] + bf2f(u[(size_t)r * 256 + tid]));
}

extern "C" void kernel_launch(void* const* d_in, const int* in_sizes, int n_in,
                              void* d_out, int out_size, void* d_ws, size_t ws_size,
                              hipStream_t stream) {
    const float* x          = (const float*)d_in[0];
    const float* W_in       = (const float*)d_in[1];
    const float* b_in       = (const float*)d_in[2];
    const float* W_wp       = (const float*)d_in[3];
    const float* b_wp       = (const float*)d_in[4];
    const float* W_fp       = (const float*)d_in[5];
    const float* b_fp       = (const float*)d_in[6];
    const float* W_bp       = (const float*)d_in[7];
    const float* b_bp       = (const float*)d_in[8];
    const float* W_out      = (const float*)d_in[9];
    const float* b_out      = (const float*)d_in[10];
    const float* norm_w_top = (const float*)d_in[11];
    const float* mamba_p[2][10];
    for (int p = 0; p < 2; ++p)
        for (int i = 0; i < 10; ++i)
            mamba_p[p][i] = (const float*)d_in[12 + p * 10 + i];

    // ---- workspace layout ----
    float* ws = (float*)d_ws;
    float* dblP[2]  = {ws + 0,       ws + 196608};
    float* hfinP[2] = {ws + 4587520, ws + 5636096};
    float* PfinP[2] = {ws + 6684672, ws + 7733248};
    unsigned short* dtsP[2] = {(unsigned short*)(ws + 393216),
                               (unsigned short*)(ws + 2490368)};

    unsigned short* us = (unsigned short*)(ws + 8781824);
    unsigned short* xn_bf   = us + 0;
    unsigned short* ssm_bf  = us + 524288;
    unsigned short* uf_bf   = us + 1572864;
    unsigned short* ub_bf   = us + 2621440;
    unsigned short* wbuf_bf = us + 3670016;
    unsigned short* xzP[2]  = {us + 4718592,  us + 8912896};
    unsigned short* xcP[2]  = {us + 13107200, us + 15204352};
    unsigned short* gP[2]   = {us + 17301504, us + 19398656};
    unsigned short* moP[2]  = {us + 21495808, us + 22544384};
    unsigned short* mof_bf  = us + 23592960;
    unsigned short* mob_bf  = us + 24641536;
    unsigned short* wb      = us + 25690112;
    unsigned short* wb_W_in  = wb + 0;
    unsigned short* wb_W_wp  = wb + 32768;
    unsigned short* wb_W_fp  = wb + 65536;
    unsigned short* wb_W_bp  = wb + 131072;
    unsigned short* wb_W_out = wb + 196608;
    unsigned short* wb_in[2]  = {wb + 229376, wb + 647168};
    unsigned short* wb_xp[2]  = {wb + 491520, wb + 909312};
    unsigned short* wb_outw[2]= {wb + 516096, wb + 933888};

    // 1. weights->bf16 + top rmsnorm
    WTab t;
    t.s[0] = W_in;            t.d[0] = wb_W_in;   t.n[0] = 32768;
    t.s[1] = W_wp;            t.d[1] = wb_W_wp;   t.n[1] = 32768;
    t.s[2] = W_fp;            t.d[2] = wb_W_fp;   t.n[2] = 65536;
    t.s[3] = W_bp;            t.d[3] = wb_W_bp;   t.n[3] = 65536;
    t.s[4] = W_out;           t.d[4] = wb_W_out;  t.n[4] = 32768;
    t.s[5] = mamba_p[0][0];   t.d[5] = wb_in[0];  t.n[5] = 262144;
    t.s[6] = mamba_p[0][3];   t.d[6] = wb_xp[0];  t.n[6] = 24576;
    t.s[7] = mamba_p[0][8];   t.d[7] = wb_outw[0];t.n[7] = 131072;
    t.s[8] = mamba_p[1][0];   t.d[8] = wb_in[1];  t.n[8] = 262144;
    t.s[9] = mamba_p[1][3];   t.d[9] = wb_xp[1];  t.n[9] = 24576;
    t.s[10]= mamba_p[1][8];   t.d[10]= wb_outw[1];t.n[10]= 131072;
    k_prep<<<dim3(256, 12), 256, 0, stream>>>(t, x, norm_w_top, xn_bf);

    // 2. ssm = xn @ W_in^T + b_in
    k_gemm_bf<<<dim3(4, 64), 256, 0, stream>>>(xn_bf, wb_W_in, b_in, ssm_bf, 256, 128);
    // 3. uf / ub / wbuf
    k_gemm3<<<dim3(4, 64, 3), 256, 0, stream>>>(xn_bf, ssm_bf, wb_W_fp, wb_W_bp, wb_W_wp,
                                                b_fp, b_bp, b_wp, uf_bf, ub_bf, wbuf_bf);
    // 4. xz = u @ in_w^T (K=256,N=1024), 128x64 tiles
    k_gemm128<<<dim3(16, 32, 2), 256, 0, stream>>>(uf_bf, ub_bf, wb_in[0], wb_in[1],
                                                   xzP[0], xzP[1], 1024, 256);
    // 5. conv + silu
    k_conv<<<dim3(2, 256, 2), 256, 0, stream>>>(xzP[0], xzP[1],
                                                mamba_p[0][1], mamba_p[1][1],
                                                mamba_p[0][2], mamba_p[1][2],
                                                xcP[0], xcP[1]);
    // 6. dbl = xconv @ xproj_w^T (K=512,N=48) -> fp32
    k_gemm2f<<<dim3(1, 64, 2), 256, 0, stream>>>(xcP[0], xcP[1], wb_xp[0], wb_xp[1],
                                                 dblP[0], dblP[1], 48, 512);
    // 7. dt = softplus(...) -> bf16
    k_dtproj<<<dim3(2, 512, 2), 256, 0, stream>>>(dblP[0], dblP[1],
                                                  mamba_p[0][4], mamba_p[1][4],
                                                  mamba_p[0][5], mamba_p[1][5],
                                                  dtsP[0], dtsP[1]);
    // 8. scan1 (local chunk scans)
    k_scan1<<<dim3(NCHUNK, 4, 8), 256, 0, stream>>>(dtsP[0], dtsP[1], xcP[0], xcP[1],
                                                    dblP[0], dblP[1],
                                                    mamba_p[0][6], mamba_p[1][6],
                                                    hfinP[0], hfinP[1], PfinP[0], PfinP[1]);
    // 9. scan2 (carry combine)
    k_scan2<<<256, 256, 0, stream>>>(hfinP[0], hfinP[1], PfinP[0], PfinP[1]);
    // 10. scan3 (replay with carry-in)
    k_scan3<<<dim3(NCHUNK, 4, 8), 256, 0, stream>>>(dtsP[0], dtsP[1], xcP[0], xcP[1],
                                                    dblP[0], dblP[1], xzP[0], xzP[1],
                                                    mamba_p[0][6], mamba_p[1][6],
                                                    mamba_p[0][7], mamba_p[1][7],
                                                    PfinP[0], PfinP[1], gP[0], gP[1]);
    // 11. mo_raw = gated @ out_w^T (K=512,N=256), 128x64 tiles
    k_gemm128<<<dim3(4, 32, 2), 256, 0, stream>>>(gP[0], gP[1], wb_outw[0], wb_outw[1],
                                                  moP[0], moP[1], 256, 512);
    // 12. postnorm both
    k_postnorm<<<dim3(NROW, 2), 256, 0, stream>>>(moP[0], moP[1],
                                                  mamba_p[0][9], mamba_p[1][9],
                                                  uf_bf, ub_bf, mof_bf, mob_bf);
    // 13. out = [wbuf*(mof+flip(mob))] @ W_out^T + b_out + x
    k_gemm_comb<<<dim3(2, 64), 256, 0, stream>>>(wbuf_bf, mof_bf, mob_bf, wb_W_out, b_out,
                                                 x, (float*)d_out, 128, 256);
}